// Round 1
// baseline (1586.302 us; speedup 1.0000x reference)
//
#include <hip/hip_runtime.h>
#include <math.h>

#define N_S 256
#define T_S 20
#define D_S 32
#define NF_S 16
#define Q_S 32
#define HDYN_S 256
#define HDIM_S 1024
#define VSTEPS_S 10
#define DT_S 0.1f
#define LOG2PI_F 1.8378770664093453f

// ---- d_out offsets (floats) ----
#define OUT_XREC 0
#define OUT_QM   5242880
#define OUT_QLV  5259264
#define OUT_ZT   5275648
#define OUT_SCAL 5603328

// ---- workspace offsets (floats) ----
#define WS_H1    0
#define WS_H2    1048576
#define WS_H3    1572864
#define WS_S0MU  1835008
#define WS_S0LV  1843200
#define WS_V0MU  1851392
#define WS_V0LV  1859584
#define WS_LOGP  1867776
#define WS_LHOOD 1872896
#define WS_KLZ   1873152
#define WS_KLW   1873408

__global__ __launch_bounds__(256) void zero_kernel(float* __restrict__ p, int n) {
    int i = blockIdx.x * 256 + threadIdx.x;
    if (i < n) p[i] = 0.f;
}

// ---------------- encoder conv: k=4, s=2, p=1, relu ----------------
template<int B, int CIN, int COUT, int HIN, int CH_STRIDE, int B_STRIDE>
__global__ __launch_bounds__(256) void conv_enc_kernel(
    const float* __restrict__ x, const float* __restrict__ w,
    const float* __restrict__ bias, float* __restrict__ out)
{
    constexpr int HOUT = HIN / 2;
    constexpr int TOTAL = B * COUT * HOUT * HOUT;
    int idx = blockIdx.x * 256 + threadIdx.x;
    if (idx >= TOTAL) return;
    int ox = idx % HOUT;
    int tmp = idx / HOUT;
    int oy = tmp % HOUT; tmp /= HOUT;
    int co = tmp % COUT;
    int b  = tmp / COUT;
    const float* xb = x + (size_t)b * B_STRIDE;
    const float* wc = w + co * CIN * 16;
    float acc = bias[co];
    for (int ci = 0; ci < CIN; ci++) {
        const float* xc  = xb + ci * CH_STRIDE;
        const float* wci = wc + ci * 16;
        #pragma unroll
        for (int ky = 0; ky < 4; ky++) {
            int iy = 2 * oy - 1 + ky;
            if (iy < 0 || iy >= HIN) continue;
            #pragma unroll
            for (int kx = 0; kx < 4; kx++) {
                int ix = 2 * ox - 1 + kx;
                if (ix < 0 || ix >= HIN) continue;
                acc = fmaf(xc[iy * HIN + ix], wci[ky * 4 + kx], acc);
            }
        }
    }
    out[idx] = fmaxf(acc, 0.f);
}

// ---------------- encoder fc: h[B,1024] -> mu,lv [B,32] ----------------
__global__ __launch_bounds__(256) void fc_enc_kernel(
    const float* __restrict__ h,
    const float* __restrict__ Wm, const float* __restrict__ bm,
    const float* __restrict__ Wl, const float* __restrict__ bl,
    float* __restrict__ mu, float* __restrict__ lv)
{
    int idx = blockIdx.x * 256 + threadIdx.x;   // N*Q = 8192 threads
    int q = idx & 31;
    int b = idx >> 5;
    const float* hb = h + (size_t)b * HDIM_S;
    float am = bm[q], al = bl[q];
    for (int k = 0; k < HDIM_S; k++) {
        float hv = hb[k];
        am = fmaf(hv, Wm[k * Q_S + q], am);
        al = fmaf(hv, Wl[k * Q_S + q], al);
    }
    mu[idx] = am;
    lv[idx] = al;
}

// ---------------- reparameterize + z0 + logp0 + qz0 outputs ----------------
__global__ __launch_bounds__(64) void reparam_kernel(
    const float* __restrict__ s0mu, const float* __restrict__ s0lv,
    const float* __restrict__ v0mu, const float* __restrict__ v0lv,
    const float* __restrict__ eps_s, const float* __restrict__ eps_v,
    float* __restrict__ qm, float* __restrict__ qlv,
    float* __restrict__ ztL, float* __restrict__ logp)
{
    int n = blockIdx.x, t = threadIdx.x;  // 64 threads
    int q = t & 31;
    float mu, lvv, ep;
    if (t < 32) { mu = v0mu[n*32+q]; lvv = v0lv[n*32+q]; ep = eps_v[n*32+q]; }
    else        { mu = s0mu[n*32+q]; lvv = s0lv[n*32+q]; ep = eps_s[n*32+q]; }
    float zv = fmaf(ep, expf(lvv), mu);
    qm[n*64 + t]  = mu;
    qlv[n*64 + t] = lvv;
    ztL[(size_t)n * T_S * 64 + t] = zv;
    float e2 = ep * ep;
    #pragma unroll
    for (int off = 32; off; off >>= 1) e2 += __shfl_down(e2, off, 64);
    if (t == 0) logp[n * T_S] = -0.5f * e2 - Q_S * LOG2PI_F;
}

// ---------------- RK4 ODE: one block per sample ----------------
__global__ __launch_bounds__(256) void ode_kernel(
    const float* __restrict__ W1, const float* __restrict__ b1,
    const float* __restrict__ W2, const float* __restrict__ b2,
    float* __restrict__ ztL, float* __restrict__ logp)
{
    __shared__ float W2s[HDYN_S * Q_S];   // 32 KB
    __shared__ float zeval[64];
    __shared__ float hsh[HDYN_S];
    __shared__ float dvred[HDYN_S];
    __shared__ float red4[4];
    int n = blockIdx.x;
    int t = threadIdx.x;

    for (int i = t; i < HDYN_S * Q_S; i += 256) W2s[i] = W2[i];
    float w1r[64];
    #pragma unroll
    for (int j = 0; j < 64; j++) w1r[j] = W1[j * HDYN_S + t];
    float b1r = b1[t];
    __syncthreads();
    float ck = 0.f;
    #pragma unroll
    for (int i = 0; i < Q_S; i++) ck = fmaf(w1r[i], W2s[t * Q_S + i], ck);

    size_t zoff = (size_t)n * T_S * 64;
    float zj = 0.f, ksumj = 0.f, zevalj = 0.f, lp = 0.f, lsum = 0.f;
    if (t < 64) { zj = ztL[zoff + t]; zevalj = zj; zeval[t] = zj; }
    if (t == 0) lp = logp[n * T_S];

    const float wc[4] = {1.f, 2.f, 2.f, 1.f};
    const float ac[3] = {0.5f * DT_S, 0.5f * DT_S, DT_S};

    for (int step = 1; step < T_S; step++) {
        for (int e = 0; e < 4; e++) {
            __syncthreads();                 // zeval published
            float pre = b1r;
            #pragma unroll
            for (int j = 0; j < 64; j++) pre = fmaf(zeval[j], w1r[j], pre);
            float hk = tanhf(pre);
            hsh[t] = hk;
            float gk = (1.f - hk * hk) * ck;
            #pragma unroll
            for (int off = 32; off; off >>= 1) gk += __shfl_down(gk, off, 64);
            if ((t & 63) == 0) red4[t >> 6] = gk;
            __syncthreads();                 // hsh, red4 ready
            {
                int i = t & 31, p = t >> 5;
                float a = 0.f;
                #pragma unroll
                for (int kk = 0; kk < 32; kk++)
                    a = fmaf(hsh[p * 32 + kk], W2s[(p * 32 + kk) * Q_S + i], a);
                dvred[t] = a;
            }
            __syncthreads();                 // dvred ready
            if (t < 64) {
                float tr = red4[0] + red4[1] + red4[2] + red4[3];
                float zv_shfl = __shfl(zevalj, (t >= 32) ? (t - 32) : t, 64);
                float kzv;
                if (t < 32) {
                    float dvi = b2[t];
                    #pragma unroll
                    for (int p = 0; p < 8; p++) dvi += dvred[p * 32 + t];
                    kzv = dvi;
                } else kzv = zv_shfl;
                if (e == 0) ksumj = kzv; else ksumj = fmaf(wc[e], kzv, ksumj);
                if (t == 0) { float kl = -tr; lsum = (e == 0) ? kl : fmaf(wc[e], kl, lsum); }
                if (e < 3) {
                    zevalj = fmaf(ac[e], kzv, zj);
                    zeval[t] = zevalj;
                } else {
                    zj = fmaf(DT_S / 6.f, ksumj, zj);
                    zevalj = zj; zeval[t] = zj;
                    ztL[zoff + step * 64 + t] = zj;
                    if (t == 0) { lp = fmaf(DT_S / 6.f, lsum, lp); logp[n * T_S + step] = lp; }
                }
            }
        }
    }
}

// ---------------- fused decoder: fc -> 3 deconvs -> sigmoid -> lhood ----------------
__global__ __launch_bounds__(256) void decoder_kernel(
    const float* __restrict__ ztL, const float* __restrict__ Wf, const float* __restrict__ bf,
    const float* __restrict__ D1, const float* __restrict__ d1,
    const float* __restrict__ D2, const float* __restrict__ d2,
    const float* __restrict__ D3, const float* __restrict__ d3,
    const float* __restrict__ X, float* __restrict__ Xrec, float* __restrict__ lhood)
{
    __shared__ float zs[Q_S];
    __shared__ float s_l[HDIM_S];        // [64,4,4]
    __shared__ float h1_l[32 * 64];      // [32,8,8]
    __shared__ float h2_l[16 * 256];     // [16,16,16]
    __shared__ float sh4[4];
    int b = blockIdx.x;     // n*T + t
    int t = threadIdx.x;

    if (t < Q_S) zs[t] = ztL[(size_t)b * 64 + Q_S + t];
    __syncthreads();

    // fc3: s = z_s @ Wf + bf
    for (int k = t; k < HDIM_S; k += 256) {
        float a = bf[k];
        #pragma unroll
        for (int q = 0; q < Q_S; q++) a = fmaf(zs[q], Wf[q * HDIM_S + k], a);
        s_l[k] = a;
    }
    __syncthreads();

    // deconv1: [64,4,4] -> [32,8,8], relu.  valid taps: ky ≡ oy (mod 2)
    for (int o = t; o < 32 * 64; o += 256) {
        int ox = o & 7, oy = (o >> 3) & 7, oc = o >> 6;
        float a = d1[oc];
        int py = oy & 1, px = ox & 1;
        #pragma unroll
        for (int sy = 0; sy < 2; sy++) {
            int ky = py + 2 * sy;
            int iy = (oy + ky - 2) >> 1;
            if ((unsigned)iy >= 4u) continue;
            #pragma unroll
            for (int sx = 0; sx < 2; sx++) {
                int kx = px + 2 * sx;
                int ix = (ox + kx - 2) >> 1;
                if ((unsigned)ix >= 4u) continue;
                const float* wp = D1 + oc * 1024 + ky * 4 + kx;
                const float* ip = s_l + iy * 4 + ix;
                #pragma unroll 8
                for (int i = 0; i < 64; i++) a = fmaf(ip[i * 16], wp[i * 16], a);
            }
        }
        h1_l[o] = fmaxf(a, 0.f);
    }
    __syncthreads();

    // deconv2: [32,8,8] -> [16,16,16], relu
    for (int o = t; o < 16 * 256; o += 256) {
        int ox = o & 15, oy = (o >> 4) & 15, oc = o >> 8;
        float a = d2[oc];
        int py = oy & 1, px = ox & 1;
        #pragma unroll
        for (int sy = 0; sy < 2; sy++) {
            int ky = py + 2 * sy;
            int iy = (oy + ky - 2) >> 1;
            if ((unsigned)iy >= 8u) continue;
            #pragma unroll
            for (int sx = 0; sx < 2; sx++) {
                int kx = px + 2 * sx;
                int ix = (ox + kx - 2) >> 1;
                if ((unsigned)ix >= 8u) continue;
                const float* wp = D2 + oc * 512 + ky * 4 + kx;
                const float* ip = h1_l + iy * 8 + ix;
                #pragma unroll 8
                for (int i = 0; i < 32; i++) a = fmaf(ip[i * 64], wp[i * 16], a);
            }
        }
        h2_l[o] = fmaxf(a, 0.f);
    }
    __syncthreads();

    // deconv3: [16,16,16] -> [1,32,32], sigmoid, write Xrec, accumulate lhood
    float ll = 0.f;
    for (int o = t; o < 1024; o += 256) {
        int ox = o & 31, oy = o >> 5;
        float a = d3[0];
        int py = oy & 1, px = ox & 1;
        #pragma unroll
        for (int sy = 0; sy < 2; sy++) {
            int ky = py + 2 * sy;
            int iy = (oy + ky - 2) >> 1;
            if ((unsigned)iy >= 16u) continue;
            #pragma unroll
            for (int sx = 0; sx < 2; sx++) {
                int kx = px + 2 * sx;
                int ix = (ox + kx - 2) >> 1;
                if ((unsigned)ix >= 16u) continue;
                const float* wp = D3 + ky * 4 + kx;
                const float* ip = h2_l + iy * 16 + ix;
                #pragma unroll
                for (int i = 0; i < 16; i++) a = fmaf(ip[i * 256], wp[i * 16], a);
            }
        }
        float xr = 1.f / (1.f + expf(-a));
        Xrec[(size_t)b * 1024 + o] = xr;
        float xv = X[(size_t)b * 1024 + o];
        ll += logf(0.001f + xr) * xv + logf(1.001f - xr) * (1.f - xv);
    }
    #pragma unroll
    for (int off = 32; off; off >>= 1) ll += __shfl_down(ll, off, 64);
    if ((t & 63) == 0) sh4[t >> 6] = ll;
    __syncthreads();
    if (t == 0) atomicAdd(&lhood[b / T_S], sh4[0] + sh4[1] + sh4[2] + sh4[3]);
}

// ---------------- kl_z per sample ----------------
__global__ __launch_bounds__(64) void klz_kernel(
    const float* __restrict__ ztL, const float* __restrict__ logp, float* __restrict__ klz)
{
    int n = blockIdx.x, t = threadIdx.x;  // 64 threads, t<20 active
    float v = 0.f;
    if (t < T_S) {
        const float* z = ztL + ((size_t)n * T_S + t) * 64;
        float s2 = 0.f;
        #pragma unroll
        for (int j = 0; j < 64; j++) s2 = fmaf(z[j], z[j], s2);
        v = logp[n * T_S + t] - (-0.5f * s2 - Q_S * LOG2PI_F);
    }
    #pragma unroll
    for (int off = 32; off; off >>= 1) v += __shfl_down(v, off, 64);
    if (t == 0) klz[n] = v;
}

// ---------------- kl_w ----------------
__global__ __launch_bounds__(256) void klw_kernel(
    const float* __restrict__ W1, const float* __restrict__ W2, float* __restrict__ klw)
{
    __shared__ float sh4[4];
    int t = threadIdx.x;
    float a = 0.f;
    for (int i = t; i < 64 * HDYN_S; i += 256) a = fmaf(W1[i], W1[i], a);
    for (int i = t; i < HDYN_S * Q_S; i += 256) a = fmaf(W2[i], W2[i], a);
    #pragma unroll
    for (int off = 32; off; off >>= 1) a += __shfl_down(a, off, 64);
    if ((t & 63) == 0) sh4[t >> 6] = a;
    __syncthreads();
    if (t == 0) klw[0] = 0.5f * (sh4[0] + sh4[1] + sh4[2] + sh4[3]);
}

// ---------------- final scalars ----------------
__global__ __launch_bounds__(256) void final_kernel(
    const float* __restrict__ lhood, const float* __restrict__ klz,
    const float* __restrict__ klw, const int* __restrict__ Ndata,
    float* __restrict__ outs)
{
    __shared__ float shA[4], shB[4];
    int t = threadIdx.x;
    float a = lhood[t];   // N == 256 == blockDim
    float b = klz[t];
    #pragma unroll
    for (int off = 32; off; off >>= 1) {
        a += __shfl_down(a, off, 64);
        b += __shfl_down(b, off, 64);
    }
    if ((t & 63) == 0) { shA[t >> 6] = a; shB[t >> 6] = b; }
    __syncthreads();
    if (t == 0) {
        float Nd = (float)Ndata[0];
        float lh = Nd * ((shA[0] + shA[1] + shA[2] + shA[3]) / 256.f);
        float kz = Nd * ((shB[0] + shB[1] + shB[2] + shB[3]) / 256.f);
        float bkw = 1.0f * klw[0];   // BETA = 1
        outs[0] = lh - kz - bkw;
        outs[1] = lh;
        outs[2] = kz;
        outs[3] = bkw;
    }
}

extern "C" void kernel_launch(void* const* d_in, const int* in_sizes, int n_in,
                              void* d_out, int out_size, void* d_ws, size_t ws_size,
                              hipStream_t stream) {
    const float* X      = (const float*)d_in[0];
    const float* eps_s0 = (const float*)d_in[1];
    const float* eps_v0 = (const float*)d_in[2];
    const float* Cs1 = (const float*)d_in[3],  *cs1 = (const float*)d_in[4];
    const float* Cs2 = (const float*)d_in[5],  *cs2 = (const float*)d_in[6];
    const float* Cs3 = (const float*)d_in[7],  *cs3 = (const float*)d_in[8];
    const float* Wsm = (const float*)d_in[9],  *bsm = (const float*)d_in[10];
    const float* Wsl = (const float*)d_in[11], *bsl = (const float*)d_in[12];
    const float* Cv1 = (const float*)d_in[13], *cv1 = (const float*)d_in[14];
    const float* Cv2 = (const float*)d_in[15], *cv2 = (const float*)d_in[16];
    const float* Cv3 = (const float*)d_in[17], *cv3 = (const float*)d_in[18];
    const float* Wvm = (const float*)d_in[19], *bvm = (const float*)d_in[20];
    const float* Wvl = (const float*)d_in[21], *bvl = (const float*)d_in[22];
    const float* W1  = (const float*)d_in[23], *b1  = (const float*)d_in[24];
    const float* W2  = (const float*)d_in[25], *b2  = (const float*)d_in[26];
    const float* Wf  = (const float*)d_in[27], *bf  = (const float*)d_in[28];
    const float* D1  = (const float*)d_in[29], *d1  = (const float*)d_in[30];
    const float* D2  = (const float*)d_in[31], *d2  = (const float*)d_in[32];
    const float* D3  = (const float*)d_in[33], *d3  = (const float*)d_in[34];
    const int*   Ndata = (const int*)d_in[35];

    float* out = (float*)d_out;
    float* ws  = (float*)d_ws;

    zero_kernel<<<1, 256, 0, stream>>>(ws + WS_LHOOD, 256);

    // ---- encoder s (input = frame 0 of X) ----
    conv_enc_kernel<256, 1, 16, 32, 1024, 20480><<<4096, 256, 0, stream>>>(X, Cs1, cs1, ws + WS_H1);
    conv_enc_kernel<256, 16, 32, 16, 256, 4096><<<2048, 256, 0, stream>>>(ws + WS_H1, Cs2, cs2, ws + WS_H2);
    conv_enc_kernel<256, 32, 64, 8, 64, 2048><<<1024, 256, 0, stream>>>(ws + WS_H2, Cs3, cs3, ws + WS_H3);
    fc_enc_kernel<<<32, 256, 0, stream>>>(ws + WS_H3, Wsm, bsm, Wsl, bsl, ws + WS_S0MU, ws + WS_S0LV);

    // ---- encoder v (input = first 10 frames as channels) ----
    conv_enc_kernel<256, 10, 16, 32, 1024, 20480><<<4096, 256, 0, stream>>>(X, Cv1, cv1, ws + WS_H1);
    conv_enc_kernel<256, 16, 32, 16, 256, 4096><<<2048, 256, 0, stream>>>(ws + WS_H1, Cv2, cv2, ws + WS_H2);
    conv_enc_kernel<256, 32, 64, 8, 64, 2048><<<1024, 256, 0, stream>>>(ws + WS_H2, Cv3, cv3, ws + WS_H3);
    fc_enc_kernel<<<32, 256, 0, stream>>>(ws + WS_H3, Wvm, bvm, Wvl, bvl, ws + WS_V0MU, ws + WS_V0LV);

    // ---- reparameterize, z0, logp0, qz0 outputs ----
    reparam_kernel<<<256, 64, 0, stream>>>(ws + WS_S0MU, ws + WS_S0LV, ws + WS_V0MU, ws + WS_V0LV,
                                           eps_s0, eps_v0,
                                           out + OUT_QM, out + OUT_QLV,
                                           out + OUT_ZT, ws + WS_LOGP);

    // ---- RK4 ODE over T-1 steps ----
    ode_kernel<<<256, 256, 0, stream>>>(W1, b1, W2, b2, out + OUT_ZT, ws + WS_LOGP);

    // ---- fused decoder + likelihood partials ----
    decoder_kernel<<<5120, 256, 0, stream>>>(out + OUT_ZT, Wf, bf, D1, d1, D2, d2, D3, d3,
                                             X, out + OUT_XREC, ws + WS_LHOOD);

    // ---- ELBO pieces ----
    klz_kernel<<<256, 64, 0, stream>>>(out + OUT_ZT, ws + WS_LOGP, ws + WS_KLZ);
    klw_kernel<<<1, 256, 0, stream>>>(W1, W2, ws + WS_KLW);
    final_kernel<<<1, 256, 0, stream>>>(ws + WS_LHOOD, ws + WS_KLZ, ws + WS_KLW, Ndata,
                                        out + OUT_SCAL);
}

// Round 2
// 1346.410 us; speedup vs baseline: 1.1782x; 1.1782x over previous
//
#include <hip/hip_runtime.h>
#include <math.h>

#define N_S 256
#define T_S 20
#define D_S 32
#define NF_S 16
#define Q_S 32
#define HDYN_S 256
#define HDIM_S 1024
#define VSTEPS_S 10
#define DT_S 0.1f
#define LOG2PI_F 1.8378770664093453f

// ---- d_out offsets (floats) ----
#define OUT_XREC 0
#define OUT_QM   5242880
#define OUT_QLV  5259264
#define OUT_ZT   5275648
#define OUT_SCAL 5603328

// ---- workspace offsets (floats) ----
// Phase overlays:
//   encoder:  A1@0 (conv1 out), A2@1048576 (conv2 out), A3@0 (conv3 out, A1 dead)
//   decoder:  WT1/WT2/WT3 @0 (A-regions dead, written by prep_dec after fc_enc_v)
#define WS_A1    0
#define WS_A3    0
#define WS_WT1   0          // 32768  [tap][ci=64][co=32]
#define WS_WT2   32768      // 8192   [tap][ci=32][co=16]
#define WS_WT3   40960      // 256    [tap][ci=16][co=1]
#define WS_A2    1048576    // 524288
#define WS_S0MU  1572864
#define WS_S0LV  1581056
#define WS_V0MU  1589248
#define WS_V0LV  1597440
#define WS_LOGP  1605632    // 5120
#define WS_LHOOD 1610752    // 256
#define WS_KLZ   1611008    // 256
#define WS_KLW   1611264    // 16
#define WS_TC    1611520    // encoder transposed weights [ci][tap][co]
#define TC_S1 (WS_TC + 0)       // 256
#define TC_V1 (WS_TC + 256)     // 2560
#define TC_S2 (WS_TC + 2816)    // 8192
#define TC_V2 (WS_TC + 11008)   // 8192
#define TC_S3 (WS_TC + 19200)   // 32768
#define TC_V3 (WS_TC + 51968)   // 32768 (end 1,696,256 floats = 6.79 MB)

__global__ __launch_bounds__(256) void zero_kernel(float* __restrict__ p, int n) {
    int i = blockIdx.x * 256 + threadIdx.x;
    if (i < n) p[i] = 0.f;
}

// ---------------- weight transposes ----------------
__device__ inline void enc_tr(const float* __restrict__ src, float* __restrict__ dst,
                              int e, int CI, int CO) {
    // dst[ci][tap][co] = src[co][ci][tap]
    int co = e % CO; int r = e / CO; int tap = r & 15; int ci = r >> 4;
    dst[e] = src[(co * CI + ci) * 16 + tap];
}
__device__ inline void dec_tr(const float* __restrict__ src, float* __restrict__ dst,
                              int e, int CI, int CO) {
    // dst[tap][ci][co] = src[co][ci][tap]
    int co = e % CO; int r = e / CO; int ci = r % CI; int tap = r / CI;
    dst[e] = src[(co * CI + ci) * 16 + tap];
}

__global__ __launch_bounds__(256) void prep_enc(
    const float* __restrict__ Cs1, const float* __restrict__ Cv1,
    const float* __restrict__ Cs2, const float* __restrict__ Cv2,
    const float* __restrict__ Cs3, const float* __restrict__ Cv3,
    float* __restrict__ ws)
{
    int idx = blockIdx.x * 256 + threadIdx.x;
    if (idx < 256)        enc_tr(Cs1, ws + TC_S1, idx,          1, 16);
    else if (idx < 2816)  enc_tr(Cv1, ws + TC_V1, idx - 256,   10, 16);
    else if (idx < 11008) enc_tr(Cs2, ws + TC_S2, idx - 2816,  16, 32);
    else if (idx < 19200) enc_tr(Cv2, ws + TC_V2, idx - 11008, 16, 32);
    else if (idx < 51968) enc_tr(Cs3, ws + TC_S3, idx - 19200, 32, 64);
    else if (idx < 84736) enc_tr(Cv3, ws + TC_V3, idx - 51968, 32, 64);
}

__global__ __launch_bounds__(256) void prep_dec(
    const float* __restrict__ D1, const float* __restrict__ D2,
    const float* __restrict__ D3, float* __restrict__ ws)
{
    int idx = blockIdx.x * 256 + threadIdx.x;
    if (idx < 32768)      dec_tr(D1, ws + WS_WT1, idx,         64, 32);
    else if (idx < 40960) dec_tr(D2, ws + WS_WT2, idx - 32768, 32, 16);
    else if (idx < 41216) dec_tr(D3, ws + WS_WT3, idx - 40960, 16, 1);
}

// ---------------- encoder conv: k=4,s=2,p=1, relu; oc-register-tiled ----------------
template<int B, int CIN, int COUT, int HIN, int OCT, int CH_STRIDE, int B_STRIDE>
__global__ __launch_bounds__(256) void conv_enc2(
    const float* __restrict__ x, const float* __restrict__ wt,   // wt: [ci][tap][co]
    const float* __restrict__ bias, float* __restrict__ out)
{
    constexpr int HOUT = HIN / 2;
    constexpr int OCG = COUT / OCT;
    int idx = blockIdx.x * 256 + threadIdx.x;
    int ox = idx % HOUT;
    int t1 = idx / HOUT;
    int oy = t1 % HOUT; t1 /= HOUT;
    int ocg = t1 % OCG;
    int b = t1 / OCG;
    float acc[OCT];
    #pragma unroll
    for (int j = 0; j < OCT; j++) acc[j] = bias[ocg * OCT + j];
    const float* xb = x + (size_t)b * B_STRIDE;
    for (int ci = 0; ci < CIN; ci++) {
        const float* xc = xb + ci * CH_STRIDE;
        const float* wci = wt + ci * 16 * COUT + ocg * OCT;
        #pragma unroll
        for (int ky = 0; ky < 4; ky++) {
            int iy = 2 * oy - 1 + ky;
            if ((unsigned)iy >= (unsigned)HIN) continue;
            #pragma unroll
            for (int kx = 0; kx < 4; kx++) {
                int ix = 2 * ox - 1 + kx;
                if ((unsigned)ix >= (unsigned)HIN) continue;
                float v = xc[iy * HIN + ix];
                const float4* w4 = (const float4*)(wci + (ky * 4 + kx) * COUT);
                #pragma unroll
                for (int jj = 0; jj < OCT / 4; jj++) {
                    float4 wv = w4[jj];
                    acc[jj*4+0] = fmaf(v, wv.x, acc[jj*4+0]);
                    acc[jj*4+1] = fmaf(v, wv.y, acc[jj*4+1]);
                    acc[jj*4+2] = fmaf(v, wv.z, acc[jj*4+2]);
                    acc[jj*4+3] = fmaf(v, wv.w, acc[jj*4+3]);
                }
            }
        }
    }
    size_t obase = ((size_t)(b * COUT + ocg * OCT) * HOUT + oy) * HOUT + ox;
    #pragma unroll
    for (int j = 0; j < OCT; j++) out[obase + (size_t)j * HOUT * HOUT] = fmaxf(acc[j], 0.f);
}

// ---------------- encoder fc: h[B,1024] -> mu,lv [B,32]; one block per sample ----------------
__global__ __launch_bounds__(256) void fc_enc2(
    const float* __restrict__ h,
    const float* __restrict__ Wm, const float* __restrict__ bm,
    const float* __restrict__ Wl, const float* __restrict__ bl,
    float* __restrict__ mu, float* __restrict__ lv)
{
    __shared__ float pm[8][32], pl[8][32];
    int b = blockIdx.x, t = threadIdx.x;
    int q = t & 31, c = t >> 5;
    const float* hb = h + (size_t)b * HDIM_S + c * 128;
    const float* wmp = Wm + (c * 128) * Q_S + q;
    const float* wlp = Wl + (c * 128) * Q_S + q;
    float am = 0.f, al = 0.f;
    #pragma unroll 4
    for (int k = 0; k < 128; k++) {
        float hv = hb[k];
        am = fmaf(hv, wmp[k * Q_S], am);
        al = fmaf(hv, wlp[k * Q_S], al);
    }
    pm[c][q] = am; pl[c][q] = al;
    __syncthreads();
    if (t < 32) {
        float s = bm[t];
        #pragma unroll
        for (int c2 = 0; c2 < 8; c2++) s += pm[c2][t];
        mu[b * Q_S + t] = s;
    } else if (t < 64) {
        int qq = t - 32;
        float s = bl[qq];
        #pragma unroll
        for (int c2 = 0; c2 < 8; c2++) s += pl[c2][qq];
        lv[b * Q_S + qq] = s;
    }
}

// ---------------- reparameterize + z0 + logp0 + qz0 outputs ----------------
__global__ __launch_bounds__(64) void reparam_kernel(
    const float* __restrict__ s0mu, const float* __restrict__ s0lv,
    const float* __restrict__ v0mu, const float* __restrict__ v0lv,
    const float* __restrict__ eps_s, const float* __restrict__ eps_v,
    float* __restrict__ qm, float* __restrict__ qlv,
    float* __restrict__ ztL, float* __restrict__ logp)
{
    int n = blockIdx.x, t = threadIdx.x;  // 64 threads
    int q = t & 31;
    float mu, lvv, ep;
    if (t < 32) { mu = v0mu[n*32+q]; lvv = v0lv[n*32+q]; ep = eps_v[n*32+q]; }
    else        { mu = s0mu[n*32+q]; lvv = s0lv[n*32+q]; ep = eps_s[n*32+q]; }
    float zv = fmaf(ep, expf(lvv), mu);
    qm[n*64 + t]  = mu;
    qlv[n*64 + t] = lvv;
    ztL[(size_t)n * T_S * 64 + t] = zv;
    float e2 = ep * ep;
    #pragma unroll
    for (int off = 32; off; off >>= 1) e2 += __shfl_down(e2, off, 64);
    if (t == 0) logp[n * T_S] = -0.5f * e2 - Q_S * LOG2PI_F;
}

// ---------------- RK4 ODE: one block per sample ----------------
__global__ __launch_bounds__(256) void ode_kernel(
    const float* __restrict__ W1, const float* __restrict__ b1,
    const float* __restrict__ W2, const float* __restrict__ b2,
    float* __restrict__ ztL, float* __restrict__ logp)
{
    __shared__ float W2s[HDYN_S * Q_S];   // 32 KB
    __shared__ float zeval[64];
    __shared__ float hsh[HDYN_S];
    __shared__ float dvred[HDYN_S];
    __shared__ float red4[4];
    int n = blockIdx.x;
    int t = threadIdx.x;

    for (int i = t; i < HDYN_S * Q_S; i += 256) W2s[i] = W2[i];
    float w1r[64];
    #pragma unroll
    for (int j = 0; j < 64; j++) w1r[j] = W1[j * HDYN_S + t];
    float b1r = b1[t];
    __syncthreads();
    float ck = 0.f;
    #pragma unroll
    for (int i = 0; i < Q_S; i++) ck = fmaf(w1r[i], W2s[t * Q_S + i], ck);

    size_t zoff = (size_t)n * T_S * 64;
    float zj = 0.f, ksumj = 0.f, zevalj = 0.f, lp = 0.f, lsum = 0.f;
    if (t < 64) { zj = ztL[zoff + t]; zevalj = zj; zeval[t] = zj; }
    if (t == 0) lp = logp[n * T_S];

    const float wc[4] = {1.f, 2.f, 2.f, 1.f};
    const float ac[3] = {0.5f * DT_S, 0.5f * DT_S, DT_S};

    for (int step = 1; step < T_S; step++) {
        for (int e = 0; e < 4; e++) {
            __syncthreads();                 // zeval published
            float pre = b1r;
            #pragma unroll
            for (int j = 0; j < 64; j++) pre = fmaf(zeval[j], w1r[j], pre);
            float hk = tanhf(pre);
            hsh[t] = hk;
            float gk = (1.f - hk * hk) * ck;
            #pragma unroll
            for (int off = 32; off; off >>= 1) gk += __shfl_down(gk, off, 64);
            if ((t & 63) == 0) red4[t >> 6] = gk;
            __syncthreads();                 // hsh, red4 ready
            {
                int i = t & 31, p = t >> 5;
                float a = 0.f;
                #pragma unroll
                for (int kk = 0; kk < 32; kk++)
                    a = fmaf(hsh[p * 32 + kk], W2s[(p * 32 + kk) * Q_S + i], a);
                dvred[t] = a;
            }
            __syncthreads();                 // dvred ready
            if (t < 64) {
                float tr = red4[0] + red4[1] + red4[2] + red4[3];
                float zv_shfl = __shfl(zevalj, (t >= 32) ? (t - 32) : t, 64);
                float kzv;
                if (t < 32) {
                    float dvi = b2[t];
                    #pragma unroll
                    for (int p = 0; p < 8; p++) dvi += dvred[p * 32 + t];
                    kzv = dvi;
                } else kzv = zv_shfl;
                if (e == 0) ksumj = kzv; else ksumj = fmaf(wc[e], kzv, ksumj);
                if (t == 0) { float kl = -tr; lsum = (e == 0) ? kl : fmaf(wc[e], kl, lsum); }
                if (e < 3) {
                    zevalj = fmaf(ac[e], kzv, zj);
                    zeval[t] = zevalj;
                } else {
                    zj = fmaf(DT_S / 6.f, ksumj, zj);
                    zevalj = zj; zeval[t] = zj;
                    ztL[zoff + step * 64 + t] = zj;
                    if (t == 0) { lp = fmaf(DT_S / 6.f, lsum, lp); logp[n * T_S + step] = lp; }
                }
            }
        }
    }
}

// ---------------- fused decoder v2 ----------------
// Activations in LDS as [pos][ci] (padded strides), weights pre-transposed [tap][ci][oc].
// Wave = parity class -> uniform taps per wave.
#define SLS 68
#define H1S 36
#define H2S 20
__global__ __launch_bounds__(256) void decoder2(
    const float* __restrict__ ztL, const float* __restrict__ Wf, const float* __restrict__ bf,
    const float* __restrict__ wt1, const float* __restrict__ d1,
    const float* __restrict__ wt2, const float* __restrict__ d2,
    const float* __restrict__ wt3, const float* __restrict__ d3,
    const float* __restrict__ X, float* __restrict__ Xrec, float* __restrict__ lhood)
{
    __shared__ float zs[32];
    __shared__ float sl[16 * SLS];
    __shared__ float h1[64 * H1S];
    __shared__ float h2[256 * H2S];
    __shared__ float wt3s[256];
    __shared__ float sh4[4];
    int bidx = blockIdx.x;
    int t = threadIdx.x;
    if (t < 32) zs[t] = ztL[(size_t)bidx * 64 + 32 + t];
    wt3s[t] = wt3[t];
    __syncthreads();

    // ---- fc3: s = z_s @ Wf + bf -> sl[pos][ci] ----
    {
        float4 acc = ((const float4*)bf)[t];
        const float4* Wf4 = (const float4*)Wf;
        #pragma unroll 4
        for (int q = 0; q < 32; q++) {
            float zq = zs[q];
            float4 wv = Wf4[q * 256 + t];
            acc.x = fmaf(zq, wv.x, acc.x);
            acc.y = fmaf(zq, wv.y, acc.y);
            acc.z = fmaf(zq, wv.z, acc.z);
            acc.w = fmaf(zq, wv.w, acc.w);
        }
        int k0 = t * 4;
        int ci = k0 >> 4;
        int p0 = k0 & 15;
        sl[(p0+0) * SLS + ci] = acc.x;
        sl[(p0+1) * SLS + ci] = acc.y;
        sl[(p0+2) * SLS + ci] = acc.z;
        sl[(p0+3) * SLS + ci] = acc.w;
    }
    __syncthreads();

    // ---- deconv1: [4,4,64] -> [8,8,32], relu. 8 oc x 1 spatial per thread ----
    {
        int w = t >> 6, l = t & 63;
        int py = w >> 1, px = w & 1;
        int ocg = l >> 4, s = l & 15;
        int a_ = s >> 2, b_ = s & 3;
        float acc[8];
        #pragma unroll
        for (int j = 0; j < 8; j++) acc[j] = d1[ocg * 8 + j];
        #pragma unroll
        for (int sy = 0; sy < 2; sy++) {
            int ky = py + 2 * sy;
            int iy = a_ + py + sy - 1;
            if ((unsigned)iy >= 4u) continue;
            #pragma unroll
            for (int sx = 0; sx < 2; sx++) {
                int kx = px + 2 * sx;
                int ix = b_ + px + sx - 1;
                if ((unsigned)ix >= 4u) continue;
                const float4* in4 = (const float4*)(sl + (iy * 4 + ix) * SLS);
                const float* wp = wt1 + (ky * 4 + kx) * 64 * 32 + ocg * 8;
                #pragma unroll 4
                for (int cc = 0; cc < 16; cc++) {
                    float4 v = in4[cc];
                    float vv[4] = {v.x, v.y, v.z, v.w};
                    const float* wr = wp + cc * 4 * 32;
                    #pragma unroll
                    for (int r = 0; r < 4; r++) {
                        const float4* w4 = (const float4*)(wr + r * 32);
                        float4 wa = w4[0], wb = w4[1];
                        float vr = vv[r];
                        acc[0] = fmaf(vr, wa.x, acc[0]);
                        acc[1] = fmaf(vr, wa.y, acc[1]);
                        acc[2] = fmaf(vr, wa.z, acc[2]);
                        acc[3] = fmaf(vr, wa.w, acc[3]);
                        acc[4] = fmaf(vr, wb.x, acc[4]);
                        acc[5] = fmaf(vr, wb.y, acc[5]);
                        acc[6] = fmaf(vr, wb.z, acc[6]);
                        acc[7] = fmaf(vr, wb.w, acc[7]);
                    }
                }
            }
        }
        int oy = 2 * a_ + py, ox = 2 * b_ + px;
        float4* o4 = (float4*)(h1 + (oy * 8 + ox) * H1S + ocg * 8);
        float4 r0, r1;
        r0.x = fmaxf(acc[0], 0.f); r0.y = fmaxf(acc[1], 0.f);
        r0.z = fmaxf(acc[2], 0.f); r0.w = fmaxf(acc[3], 0.f);
        r1.x = fmaxf(acc[4], 0.f); r1.y = fmaxf(acc[5], 0.f);
        r1.z = fmaxf(acc[6], 0.f); r1.w = fmaxf(acc[7], 0.f);
        o4[0] = r0; o4[1] = r1;
    }
    __syncthreads();

    // ---- deconv2: [8,8,32] -> [16,16,16], relu. 16 oc x 1 spatial per thread ----
    {
        int w = t >> 6, l = t & 63;
        int py = w >> 1, px = w & 1;
        int a_ = l >> 3, b_ = l & 7;
        float acc[16];
        #pragma unroll
        for (int j = 0; j < 16; j++) acc[j] = d2[j];
        #pragma unroll
        for (int sy = 0; sy < 2; sy++) {
            int ky = py + 2 * sy;
            int iy = a_ + py + sy - 1;
            if ((unsigned)iy >= 8u) continue;
            #pragma unroll
            for (int sx = 0; sx < 2; sx++) {
                int kx = px + 2 * sx;
                int ix = b_ + px + sx - 1;
                if ((unsigned)ix >= 8u) continue;
                const float4* in4 = (const float4*)(h1 + (iy * 8 + ix) * H1S);
                const float* wp = wt2 + (ky * 4 + kx) * 32 * 16;
                #pragma unroll 2
                for (int cc = 0; cc < 8; cc++) {
                    float4 v = in4[cc];
                    float vv[4] = {v.x, v.y, v.z, v.w};
                    const float* wr = wp + cc * 4 * 16;
                    #pragma unroll
                    for (int r = 0; r < 4; r++) {
                        const float4* w4 = (const float4*)(wr + r * 16);
                        float4 wa = w4[0], wb = w4[1], wcq = w4[2], wd = w4[3];
                        float vr = vv[r];
                        acc[0]  = fmaf(vr, wa.x, acc[0]);
                        acc[1]  = fmaf(vr, wa.y, acc[1]);
                        acc[2]  = fmaf(vr, wa.z, acc[2]);
                        acc[3]  = fmaf(vr, wa.w, acc[3]);
                        acc[4]  = fmaf(vr, wb.x, acc[4]);
                        acc[5]  = fmaf(vr, wb.y, acc[5]);
                        acc[6]  = fmaf(vr, wb.z, acc[6]);
                        acc[7]  = fmaf(vr, wb.w, acc[7]);
                        acc[8]  = fmaf(vr, wcq.x, acc[8]);
                        acc[9]  = fmaf(vr, wcq.y, acc[9]);
                        acc[10] = fmaf(vr, wcq.z, acc[10]);
                        acc[11] = fmaf(vr, wcq.w, acc[11]);
                        acc[12] = fmaf(vr, wd.x, acc[12]);
                        acc[13] = fmaf(vr, wd.y, acc[13]);
                        acc[14] = fmaf(vr, wd.z, acc[14]);
                        acc[15] = fmaf(vr, wd.w, acc[15]);
                    }
                }
            }
        }
        int oy = 2 * a_ + py, ox = 2 * b_ + px;
        float4* o4 = (float4*)(h2 + (oy * 16 + ox) * H2S);
        #pragma unroll
        for (int jj = 0; jj < 4; jj++) {
            float4 r;
            r.x = fmaxf(acc[jj*4+0], 0.f);
            r.y = fmaxf(acc[jj*4+1], 0.f);
            r.z = fmaxf(acc[jj*4+2], 0.f);
            r.w = fmaxf(acc[jj*4+3], 0.f);
            o4[jj] = r;
        }
    }
    __syncthreads();

    // ---- deconv3: [16,16,16] -> [32,32], sigmoid, lhood. 4 spatial per thread ----
    {
        int w = t >> 6, l = t & 63;
        int py = w >> 1, px = w & 1;
        int a_ = l >> 2, bb = l & 3;
        float acc[4];
        float d30 = d3[0];
        #pragma unroll
        for (int k = 0; k < 4; k++) acc[k] = d30;
        #pragma unroll
        for (int sy = 0; sy < 2; sy++) {
            int ky = py + 2 * sy;
            int iy = a_ + py + sy - 1;
            if ((unsigned)iy >= 16u) continue;
            #pragma unroll
            for (int sx = 0; sx < 2; sx++) {
                int kx = px + 2 * sx;
                const float* wv = wt3s + (ky * 4 + kx) * 16;
                #pragma unroll
                for (int k = 0; k < 4; k++) {
                    int ix = bb + 4 * k + px + sx - 1;
                    if ((unsigned)ix >= 16u) continue;
                    const float4* in4 = (const float4*)(h2 + (iy * 16 + ix) * H2S);
                    #pragma unroll
                    for (int cc = 0; cc < 4; cc++) {
                        float4 v = in4[cc];
                        const float4* w4 = (const float4*)(wv + cc * 4);
                        float4 wq = w4[0];
                        acc[k] = fmaf(v.x, wq.x, acc[k]);
                        acc[k] = fmaf(v.y, wq.y, acc[k]);
                        acc[k] = fmaf(v.z, wq.z, acc[k]);
                        acc[k] = fmaf(v.w, wq.w, acc[k]);
                    }
                }
            }
        }
        int oy = 2 * a_ + py;
        float ll = 0.f;
        #pragma unroll
        for (int k = 0; k < 4; k++) {
            int ox = 2 * (bb + 4 * k) + px;
            float xr = 1.f / (1.f + expf(-acc[k]));
            size_t oi = (size_t)bidx * 1024 + oy * 32 + ox;
            Xrec[oi] = xr;
            float xv = X[oi];
            ll += logf(0.001f + xr) * xv + logf(1.001f - xr) * (1.f - xv);
        }
        #pragma unroll
        for (int off = 32; off; off >>= 1) ll += __shfl_down(ll, off, 64);
        if ((t & 63) == 0) sh4[t >> 6] = ll;
    }
    __syncthreads();
    if (t == 0) atomicAdd(&lhood[bidx / T_S], sh4[0] + sh4[1] + sh4[2] + sh4[3]);
}

// ---------------- kl_z per sample ----------------
__global__ __launch_bounds__(64) void klz_kernel(
    const float* __restrict__ ztL, const float* __restrict__ logp, float* __restrict__ klz)
{
    int n = blockIdx.x, t = threadIdx.x;
    float v = 0.f;
    if (t < T_S) {
        const float* z = ztL + ((size_t)n * T_S + t) * 64;
        float s2 = 0.f;
        #pragma unroll
        for (int j = 0; j < 64; j++) s2 = fmaf(z[j], z[j], s2);
        v = logp[n * T_S + t] - (-0.5f * s2 - Q_S * LOG2PI_F);
    }
    #pragma unroll
    for (int off = 32; off; off >>= 1) v += __shfl_down(v, off, 64);
    if (t == 0) klz[n] = v;
}

// ---------------- kl_w ----------------
__global__ __launch_bounds__(256) void klw_kernel(
    const float* __restrict__ W1, const float* __restrict__ W2, float* __restrict__ klw)
{
    __shared__ float sh4[4];
    int t = threadIdx.x;
    float a = 0.f;
    for (int i = t; i < 64 * HDYN_S; i += 256) a = fmaf(W1[i], W1[i], a);
    for (int i = t; i < HDYN_S * Q_S; i += 256) a = fmaf(W2[i], W2[i], a);
    #pragma unroll
    for (int off = 32; off; off >>= 1) a += __shfl_down(a, off, 64);
    if ((t & 63) == 0) sh4[t >> 6] = a;
    __syncthreads();
    if (t == 0) klw[0] = 0.5f * (sh4[0] + sh4[1] + sh4[2] + sh4[3]);
}

// ---------------- final scalars ----------------
__global__ __launch_bounds__(256) void final_kernel(
    const float* __restrict__ lhood, const float* __restrict__ klz,
    const float* __restrict__ klw, const int* __restrict__ Ndata,
    float* __restrict__ outs)
{
    __shared__ float shA[4], shB[4];
    int t = threadIdx.x;
    float a = lhood[t];
    float b = klz[t];
    #pragma unroll
    for (int off = 32; off; off >>= 1) {
        a += __shfl_down(a, off, 64);
        b += __shfl_down(b, off, 64);
    }
    if ((t & 63) == 0) { shA[t >> 6] = a; shB[t >> 6] = b; }
    __syncthreads();
    if (t == 0) {
        float Nd = (float)Ndata[0];
        float lh = Nd * ((shA[0] + shA[1] + shA[2] + shA[3]) / 256.f);
        float kz = Nd * ((shB[0] + shB[1] + shB[2] + shB[3]) / 256.f);
        float bkw = 1.0f * klw[0];
        outs[0] = lh - kz - bkw;
        outs[1] = lh;
        outs[2] = kz;
        outs[3] = bkw;
    }
}

extern "C" void kernel_launch(void* const* d_in, const int* in_sizes, int n_in,
                              void* d_out, int out_size, void* d_ws, size_t ws_size,
                              hipStream_t stream) {
    const float* X      = (const float*)d_in[0];
    const float* eps_s0 = (const float*)d_in[1];
    const float* eps_v0 = (const float*)d_in[2];
    const float* Cs1 = (const float*)d_in[3],  *cs1 = (const float*)d_in[4];
    const float* Cs2 = (const float*)d_in[5],  *cs2 = (const float*)d_in[6];
    const float* Cs3 = (const float*)d_in[7],  *cs3 = (const float*)d_in[8];
    const float* Wsm = (const float*)d_in[9],  *bsm = (const float*)d_in[10];
    const float* Wsl = (const float*)d_in[11], *bsl = (const float*)d_in[12];
    const float* Cv1 = (const float*)d_in[13], *cv1 = (const float*)d_in[14];
    const float* Cv2 = (const float*)d_in[15], *cv2 = (const float*)d_in[16];
    const float* Cv3 = (const float*)d_in[17], *cv3 = (const float*)d_in[18];
    const float* Wvm = (const float*)d_in[19], *bvm = (const float*)d_in[20];
    const float* Wvl = (const float*)d_in[21], *bvl = (const float*)d_in[22];
    const float* W1  = (const float*)d_in[23], *b1  = (const float*)d_in[24];
    const float* W2  = (const float*)d_in[25], *b2  = (const float*)d_in[26];
    const float* Wf  = (const float*)d_in[27], *bf  = (const float*)d_in[28];
    const float* D1  = (const float*)d_in[29], *d1  = (const float*)d_in[30];
    const float* D2  = (const float*)d_in[31], *d2  = (const float*)d_in[32];
    const float* D3  = (const float*)d_in[33], *d3  = (const float*)d_in[34];
    const int*   Ndata = (const int*)d_in[35];

    float* out = (float*)d_out;
    float* ws  = (float*)d_ws;

    zero_kernel<<<1, 256, 0, stream>>>(ws + WS_LHOOD, 256);
    prep_enc<<<331, 256, 0, stream>>>(Cs1, Cv1, Cs2, Cv2, Cs3, Cv3, ws);

    // ---- encoder s (frame 0) ----
    conv_enc2<256, 1, 16, 32, 16, 1024, 20480><<<256, 256, 0, stream>>>(X, ws + TC_S1, cs1, ws + WS_A1);
    conv_enc2<256, 16, 32, 16, 8, 256, 4096><<<256, 256, 0, stream>>>(ws + WS_A1, ws + TC_S2, cs2, ws + WS_A2);
    conv_enc2<256, 32, 64, 8, 8, 64, 2048><<<128, 256, 0, stream>>>(ws + WS_A2, ws + TC_S3, cs3, ws + WS_A3);
    fc_enc2<<<256, 256, 0, stream>>>(ws + WS_A3, Wsm, bsm, Wsl, bsl, ws + WS_S0MU, ws + WS_S0LV);

    // ---- encoder v (10 frames as channels) ----
    conv_enc2<256, 10, 16, 32, 16, 1024, 20480><<<256, 256, 0, stream>>>(X, ws + TC_V1, cv1, ws + WS_A1);
    conv_enc2<256, 16, 32, 16, 8, 256, 4096><<<256, 256, 0, stream>>>(ws + WS_A1, ws + TC_V2, cv2, ws + WS_A2);
    conv_enc2<256, 32, 64, 8, 8, 64, 2048><<<128, 256, 0, stream>>>(ws + WS_A2, ws + TC_V3, cv3, ws + WS_A3);
    fc_enc2<<<256, 256, 0, stream>>>(ws + WS_A3, Wvm, bvm, Wvl, bvl, ws + WS_V0MU, ws + WS_V0LV);

    // ---- reparameterize ----
    reparam_kernel<<<256, 64, 0, stream>>>(ws + WS_S0MU, ws + WS_S0LV, ws + WS_V0MU, ws + WS_V0LV,
                                           eps_s0, eps_v0,
                                           out + OUT_QM, out + OUT_QLV,
                                           out + OUT_ZT, ws + WS_LOGP);

    // ---- decoder weight transpose (A-regions now dead) ----
    prep_dec<<<161, 256, 0, stream>>>(D1, D2, D3, ws);

    // ---- RK4 ODE ----
    ode_kernel<<<256, 256, 0, stream>>>(W1, b1, W2, b2, out + OUT_ZT, ws + WS_LOGP);

    // ---- fused decoder ----
    decoder2<<<5120, 256, 0, stream>>>(out + OUT_ZT, Wf, bf,
                                       ws + WS_WT1, d1, ws + WS_WT2, d2, ws + WS_WT3, d3,
                                       X, out + OUT_XREC, ws + WS_LHOOD);

    // ---- ELBO pieces ----
    klz_kernel<<<256, 64, 0, stream>>>(out + OUT_ZT, ws + WS_LOGP, ws + WS_KLZ);
    klw_kernel<<<1, 256, 0, stream>>>(W1, W2, ws + WS_KLW);
    final_kernel<<<1, 256, 0, stream>>>(ws + WS_LHOOD, ws + WS_KLZ, ws + WS_KLW, Ndata,
                                        out + OUT_SCAL);
}

// Round 3
// 988.092 us; speedup vs baseline: 1.6054x; 1.3626x over previous
//
#include <hip/hip_runtime.h>
#include <math.h>

#define N_S 256
#define T_S 20
#define D_S 32
#define NF_S 16
#define Q_S 32
#define HDYN_S 256
#define HDIM_S 1024
#define VSTEPS_S 10
#define DT_S 0.1f
#define LOG2PI_F 1.8378770664093453f

// ---- d_out offsets (floats) ----
#define OUT_XREC 0
#define OUT_QM   5242880
#define OUT_QLV  5259264
#define OUT_ZT   5275648
#define OUT_SCAL 5603328

// ---- workspace offsets (floats) ----
#define WS_A1    0          // conv1 out [b][16][16][16] = 1,048,576
#define WS_A3    0          // conv3 out [b][64][4][4]   =   262,144 (A1 dead)
#define WS_WT1   0          // decoder: 32768  [tap][ci=64][co=32]
#define WS_WT2   32768      //          8192   [tap][ci=32][co=16]
#define WS_WT3   40960      //          256    [tap][ci=16]
#define WS_A2    1048576    // conv2 out [b][32][8][8] = 524,288
#define WS_S0MU  1572864
#define WS_S0LV  1581056
#define WS_V0MU  1589248
#define WS_V0LV  1597440
#define WS_LOGP  1605632
#define WS_LHOOD 1610752
#define WS_KLZ   1611008
#define WS_KLW   1611264
#define WS_TC    1611520    // encoder transposed weights [ci][tap][co]
#define TC_S1 (WS_TC + 0)       // 256
#define TC_V1 (WS_TC + 256)     // 2560
#define TC_S2 (WS_TC + 2816)    // 8192
#define TC_V2 (WS_TC + 11008)   // 8192
#define TC_S3 (WS_TC + 19200)   // 32768
#define TC_V3 (WS_TC + 51968)   // 32768

__global__ __launch_bounds__(256) void zero_kernel(float* __restrict__ p, int n) {
    int i = blockIdx.x * 256 + threadIdx.x;
    if (i < n) p[i] = 0.f;
}

// ---------------- weight transposes ----------------
__device__ inline void enc_tr(const float* __restrict__ src, float* __restrict__ dst,
                              int e, int CI, int CO) {
    int co = e % CO; int r = e / CO; int tap = r & 15; int ci = r >> 4;
    dst[e] = src[(co * CI + ci) * 16 + tap];
}
__device__ inline void dec_tr(const float* __restrict__ src, float* __restrict__ dst,
                              int e, int CI, int CO) {
    int co = e % CO; int r = e / CO; int ci = r % CI; int tap = r / CI;
    dst[e] = src[(co * CI + ci) * 16 + tap];
}

__global__ __launch_bounds__(256) void prep_enc(
    const float* __restrict__ Cs1, const float* __restrict__ Cv1,
    const float* __restrict__ Cs2, const float* __restrict__ Cv2,
    const float* __restrict__ Cs3, const float* __restrict__ Cv3,
    float* __restrict__ ws)
{
    int idx = blockIdx.x * 256 + threadIdx.x;
    if (idx < 256)        enc_tr(Cs1, ws + TC_S1, idx,          1, 16);
    else if (idx < 2816)  enc_tr(Cv1, ws + TC_V1, idx - 256,   10, 16);
    else if (idx < 11008) enc_tr(Cs2, ws + TC_S2, idx - 2816,  16, 32);
    else if (idx < 19200) enc_tr(Cv2, ws + TC_V2, idx - 11008, 16, 32);
    else if (idx < 51968) enc_tr(Cs3, ws + TC_S3, idx - 19200, 32, 64);
    else if (idx < 84736) enc_tr(Cv3, ws + TC_V3, idx - 51968, 32, 64);
}

__global__ __launch_bounds__(256) void prep_dec(
    const float* __restrict__ D1, const float* __restrict__ D2,
    const float* __restrict__ D3, float* __restrict__ ws)
{
    int idx = blockIdx.x * 256 + threadIdx.x;
    if (idx < 32768)      dec_tr(D1, ws + WS_WT1, idx,         64, 32);
    else if (idx < 40960) dec_tr(D2, ws + WS_WT2, idx - 32768, 32, 16);
    else if (idx < 41216) dec_tr(D3, ws + WS_WT3, idx - 40960, 16, 1);
}

// ---------------- conv1: k=4,s=2,p=1, relu; LDS-resident, block=image ----------------
template<int CIN>
__global__ __launch_bounds__(256) void conv1_lds(
    const float* __restrict__ x, const float* __restrict__ wt,   // wt: [ci][tap][16]
    const float* __restrict__ bias, float* __restrict__ out)     // out: [b][16][16][16]
{
    __shared__ float xin[CIN * 1056];   // ci*1056 + iy*33 + ix
    __shared__ float wl[CIN * 256];
    __shared__ float bl[16];
    int b = blockIdx.x, t = threadIdx.x;
    for (int e = t; e < CIN * 1024; e += 256) {
        int ci = e >> 10, r = e & 1023, iy = r >> 5, ix = r & 31;
        xin[ci * 1056 + iy * 33 + ix] = x[(size_t)b * 20480 + e];
    }
    for (int e = t; e < CIN * 256; e += 256) wl[e] = wt[e];
    if (t < 16) bl[t] = bias[t];
    __syncthreads();

    int ocq = t >> 7, p = t & 127;     // 2 groups x 8 oc
    int oy = p >> 3, pb = p & 7;       // ox in {2pb, 2pb+1}
    float acc0[8], acc1[8];
    #pragma unroll
    for (int j = 0; j < 8; j++) { acc0[j] = bl[ocq * 8 + j]; acc1[j] = acc0[j]; }
    for (int ci = 0; ci < CIN; ci++) {
        const float* xc = xin + ci * 1056;
        const float* wc = wl + ci * 256 + ocq * 8;
        #pragma unroll
        for (int ky = 0; ky < 4; ky++) {
            int iy = 2 * oy - 1 + ky;
            if ((unsigned)iy >= 32u) continue;
            const float* xr = xc + iy * 33;
            #pragma unroll
            for (int kx = 0; kx < 4; kx++) {
                int ix0 = 4 * pb - 1 + kx, ix1 = ix0 + 2;
                float v0 = ((unsigned)ix0 < 32u) ? xr[ix0] : 0.f;
                float v1 = ((unsigned)ix1 < 32u) ? xr[ix1] : 0.f;
                const float4* w4 = (const float4*)(wc + (ky * 4 + kx) * 16);
                float4 wa = w4[0], wb = w4[1];
                acc0[0] = fmaf(v0, wa.x, acc0[0]); acc1[0] = fmaf(v1, wa.x, acc1[0]);
                acc0[1] = fmaf(v0, wa.y, acc0[1]); acc1[1] = fmaf(v1, wa.y, acc1[1]);
                acc0[2] = fmaf(v0, wa.z, acc0[2]); acc1[2] = fmaf(v1, wa.z, acc1[2]);
                acc0[3] = fmaf(v0, wa.w, acc0[3]); acc1[3] = fmaf(v1, wa.w, acc1[3]);
                acc0[4] = fmaf(v0, wb.x, acc0[4]); acc1[4] = fmaf(v1, wb.x, acc1[4]);
                acc0[5] = fmaf(v0, wb.y, acc0[5]); acc1[5] = fmaf(v1, wb.y, acc1[5]);
                acc0[6] = fmaf(v0, wb.z, acc0[6]); acc1[6] = fmaf(v1, wb.z, acc1[6]);
                acc0[7] = fmaf(v0, wb.w, acc0[7]); acc1[7] = fmaf(v1, wb.w, acc1[7]);
            }
        }
    }
    size_t ob = (size_t)b * 4096 + (size_t)(ocq * 8) * 256 + oy * 16 + 2 * pb;
    #pragma unroll
    for (int j = 0; j < 8; j++) {
        float2 r; r.x = fmaxf(acc0[j], 0.f); r.y = fmaxf(acc1[j], 0.f);
        *(float2*)(out + ob + (size_t)j * 256) = r;
    }
}

// ---------------- conv2: [16,16,16]->[32,8,8]; LDS-resident, block=image ----------------
__global__ __launch_bounds__(256) void conv2_lds(
    const float* __restrict__ a1, const float* __restrict__ wt,  // wt: [ci][tap][32]
    const float* __restrict__ bias, float* __restrict__ out)     // out: [b][32][8][8]
{
    __shared__ float xin[16 * 272];   // ci*272 + iy*17 + ix
    __shared__ float wl[8192];
    __shared__ float bl[32];
    int b = blockIdx.x, t = threadIdx.x;
    for (int e = t; e < 4096; e += 256) {
        int ci = e >> 8, r = e & 255, iy = r >> 4, ix = r & 15;
        xin[ci * 272 + iy * 17 + ix] = a1[(size_t)b * 4096 + e];
    }
    for (int e = t; e < 2048; e += 256) ((float4*)wl)[e] = ((const float4*)wt)[e];
    if (t < 32) bl[t] = bias[t];
    __syncthreads();

    int ocq = t >> 5, p = t & 31;    // 8 groups x 4 oc
    int pa = p >> 2, pb = p & 3;     // oy=pa, ox in {2pb, 2pb+1}
    float acc0[4], acc1[4];
    #pragma unroll
    for (int j = 0; j < 4; j++) { acc0[j] = bl[ocq * 4 + j]; acc1[j] = acc0[j]; }
    for (int ci = 0; ci < 16; ci++) {
        const float* xc = xin + ci * 272;
        const float* wc = wl + ci * 512 + ocq * 4;
        #pragma unroll
        for (int ky = 0; ky < 4; ky++) {
            int iy = 2 * pa - 1 + ky;
            if ((unsigned)iy >= 16u) continue;
            const float* xr = xc + iy * 17;
            #pragma unroll
            for (int kx = 0; kx < 4; kx++) {
                int ix0 = 4 * pb - 1 + kx, ix1 = ix0 + 2;
                float v0 = ((unsigned)ix0 < 16u) ? xr[ix0] : 0.f;
                float v1 = ((unsigned)ix1 < 16u) ? xr[ix1] : 0.f;
                float4 wv = *(const float4*)(wc + (ky * 4 + kx) * 32);
                acc0[0] = fmaf(v0, wv.x, acc0[0]); acc1[0] = fmaf(v1, wv.x, acc1[0]);
                acc0[1] = fmaf(v0, wv.y, acc0[1]); acc1[1] = fmaf(v1, wv.y, acc1[1]);
                acc0[2] = fmaf(v0, wv.z, acc0[2]); acc1[2] = fmaf(v1, wv.z, acc1[2]);
                acc0[3] = fmaf(v0, wv.w, acc0[3]); acc1[3] = fmaf(v1, wv.w, acc1[3]);
            }
        }
    }
    size_t ob = (size_t)b * 2048 + (size_t)(ocq * 4) * 64 + pa * 8 + 2 * pb;
    #pragma unroll
    for (int j = 0; j < 4; j++) {
        float2 r; r.x = fmaxf(acc0[j], 0.f); r.y = fmaxf(acc1[j], 0.f);
        *(float2*)(out + ob + (size_t)j * 64) = r;
    }
}

// ---------------- conv3: [32,8,8]->[64,4,4]; block=(image, oc-half) ----------------
__global__ __launch_bounds__(256) void conv3_lds(
    const float* __restrict__ a2, const float* __restrict__ wt,  // wt: [ci][tap][64]
    const float* __restrict__ bias, float* __restrict__ out)     // out: [b][64][4][4]
{
    __shared__ float xin[32 * 72];    // ci*72 + iy*9 + ix
    __shared__ float wl[16384];       // [ci][tap][32] slice
    __shared__ float bl[32];
    int b = blockIdx.x, h = blockIdx.y, t = threadIdx.x;
    for (int e = t; e < 2048; e += 256) {
        int ci = e >> 6, r = e & 63, iy = r >> 3, ix = r & 7;
        xin[ci * 72 + iy * 9 + ix] = a2[(size_t)b * 2048 + e];
    }
    for (int e4 = t; e4 < 4096; e4 += 256) {
        int grp = e4 >> 3, c4 = e4 & 7;
        ((float4*)wl)[e4] = ((const float4*)(wt + grp * 64 + h * 32))[c4];
    }
    if (t < 32) bl[t] = bias[h * 32 + t];
    __syncthreads();

    int ocq = t >> 4, p = t & 15;    // 16 groups x 2 oc
    int pa = p >> 2, pb = p & 3;
    float a0 = bl[ocq * 2], a1 = bl[ocq * 2 + 1];
    for (int ci = 0; ci < 32; ci++) {
        const float* xc = xin + ci * 72;
        const float* wc = wl + ci * 512 + ocq * 2;
        #pragma unroll
        for (int ky = 0; ky < 4; ky++) {
            int iy = 2 * pa - 1 + ky;
            if ((unsigned)iy >= 8u) continue;
            const float* xr = xc + iy * 9;
            #pragma unroll
            for (int kx = 0; kx < 4; kx++) {
                int ix = 2 * pb - 1 + kx;
                if ((unsigned)ix >= 8u) continue;
                float v = xr[ix];
                float2 wv = *(const float2*)(wc + (ky * 4 + kx) * 32);
                a0 = fmaf(v, wv.x, a0);
                a1 = fmaf(v, wv.y, a1);
            }
        }
    }
    size_t ob = (size_t)b * 1024 + (size_t)(h * 32 + ocq * 2) * 16 + pa * 4 + pb;
    out[ob] = fmaxf(a0, 0.f);
    out[ob + 16] = fmaxf(a1, 0.f);
}

// ---------------- encoder fc ----------------
__global__ __launch_bounds__(256) void fc_enc2(
    const float* __restrict__ h,
    const float* __restrict__ Wm, const float* __restrict__ bm,
    const float* __restrict__ Wl, const float* __restrict__ bl,
    float* __restrict__ mu, float* __restrict__ lv)
{
    __shared__ float pm[8][32], pl[8][32];
    int b = blockIdx.x, t = threadIdx.x;
    int q = t & 31, c = t >> 5;
    const float* hb = h + (size_t)b * HDIM_S + c * 128;
    const float* wmp = Wm + (c * 128) * Q_S + q;
    const float* wlp = Wl + (c * 128) * Q_S + q;
    float am = 0.f, al = 0.f;
    #pragma unroll 4
    for (int k = 0; k < 128; k++) {
        float hv = hb[k];
        am = fmaf(hv, wmp[k * Q_S], am);
        al = fmaf(hv, wlp[k * Q_S], al);
    }
    pm[c][q] = am; pl[c][q] = al;
    __syncthreads();
    if (t < 32) {
        float s = bm[t];
        #pragma unroll
        for (int c2 = 0; c2 < 8; c2++) s += pm[c2][t];
        mu[b * Q_S + t] = s;
    } else if (t < 64) {
        int qq = t - 32;
        float s = bl[qq];
        #pragma unroll
        for (int c2 = 0; c2 < 8; c2++) s += pl[c2][qq];
        lv[b * Q_S + qq] = s;
    }
}

// ---------------- reparameterize ----------------
__global__ __launch_bounds__(64) void reparam_kernel(
    const float* __restrict__ s0mu, const float* __restrict__ s0lv,
    const float* __restrict__ v0mu, const float* __restrict__ v0lv,
    const float* __restrict__ eps_s, const float* __restrict__ eps_v,
    float* __restrict__ qm, float* __restrict__ qlv,
    float* __restrict__ ztL, float* __restrict__ logp)
{
    int n = blockIdx.x, t = threadIdx.x;
    int q = t & 31;
    float mu, lvv, ep;
    if (t < 32) { mu = v0mu[n*32+q]; lvv = v0lv[n*32+q]; ep = eps_v[n*32+q]; }
    else        { mu = s0mu[n*32+q]; lvv = s0lv[n*32+q]; ep = eps_s[n*32+q]; }
    float zv = fmaf(ep, expf(lvv), mu);
    qm[n*64 + t]  = mu;
    qlv[n*64 + t] = lvv;
    ztL[(size_t)n * T_S * 64 + t] = zv;
    float e2 = ep * ep;
    #pragma unroll
    for (int off = 32; off; off >>= 1) e2 += __shfl_down(e2, off, 64);
    if (t == 0) logp[n * T_S] = -0.5f * e2 - Q_S * LOG2PI_F;
}

// ---------------- RK4 ODE ----------------
__global__ __launch_bounds__(256) void ode_kernel(
    const float* __restrict__ W1, const float* __restrict__ b1,
    const float* __restrict__ W2, const float* __restrict__ b2,
    float* __restrict__ ztL, float* __restrict__ logp)
{
    __shared__ float W2s[HDYN_S * Q_S];
    __shared__ float zeval[64];
    __shared__ float hsh[HDYN_S];
    __shared__ float dvred[HDYN_S];
    __shared__ float red4[4];
    int n = blockIdx.x;
    int t = threadIdx.x;

    for (int i = t; i < HDYN_S * Q_S; i += 256) W2s[i] = W2[i];
    float w1r[64];
    #pragma unroll
    for (int j = 0; j < 64; j++) w1r[j] = W1[j * HDYN_S + t];
    float b1r = b1[t];
    __syncthreads();
    float ck = 0.f;
    #pragma unroll
    for (int i = 0; i < Q_S; i++) ck = fmaf(w1r[i], W2s[t * Q_S + i], ck);

    size_t zoff = (size_t)n * T_S * 64;
    float zj = 0.f, ksumj = 0.f, zevalj = 0.f, lp = 0.f, lsum = 0.f;
    if (t < 64) { zj = ztL[zoff + t]; zevalj = zj; zeval[t] = zj; }
    if (t == 0) lp = logp[n * T_S];

    const float wc[4] = {1.f, 2.f, 2.f, 1.f};
    const float ac[3] = {0.5f * DT_S, 0.5f * DT_S, DT_S};

    for (int step = 1; step < T_S; step++) {
        for (int e = 0; e < 4; e++) {
            __syncthreads();
            float pre = b1r;
            #pragma unroll
            for (int j = 0; j < 64; j++) pre = fmaf(zeval[j], w1r[j], pre);
            float hk = tanhf(pre);
            hsh[t] = hk;
            float gk = (1.f - hk * hk) * ck;
            #pragma unroll
            for (int off = 32; off; off >>= 1) gk += __shfl_down(gk, off, 64);
            if ((t & 63) == 0) red4[t >> 6] = gk;
            __syncthreads();
            {
                int i = t & 31, p = t >> 5;
                float a = 0.f;
                #pragma unroll
                for (int kk = 0; kk < 32; kk++)
                    a = fmaf(hsh[p * 32 + kk], W2s[(p * 32 + kk) * Q_S + i], a);
                dvred[t] = a;
            }
            __syncthreads();
            if (t < 64) {
                float tr = red4[0] + red4[1] + red4[2] + red4[3];
                float zv_shfl = __shfl(zevalj, (t >= 32) ? (t - 32) : t, 64);
                float kzv;
                if (t < 32) {
                    float dvi = b2[t];
                    #pragma unroll
                    for (int p = 0; p < 8; p++) dvi += dvred[p * 32 + t];
                    kzv = dvi;
                } else kzv = zv_shfl;
                if (e == 0) ksumj = kzv; else ksumj = fmaf(wc[e], kzv, ksumj);
                if (t == 0) { float kl = -tr; lsum = (e == 0) ? kl : fmaf(wc[e], kl, lsum); }
                if (e < 3) {
                    zevalj = fmaf(ac[e], kzv, zj);
                    zeval[t] = zevalj;
                } else {
                    zj = fmaf(DT_S / 6.f, ksumj, zj);
                    zevalj = zj; zeval[t] = zj;
                    ztL[zoff + step * 64 + t] = zj;
                    if (t == 0) { lp = fmaf(DT_S / 6.f, lsum, lp); logp[n * T_S + step] = lp; }
                }
            }
        }
    }
}

// ---------------- fused decoder v3 ----------------
// sl: [pos][68] (aliased with h2); h1: [pos][36]; h2: oy*324 + ox*20 + c
__global__ __launch_bounds__(256, 5) void decoder3(
    const float* __restrict__ ztL, const float* __restrict__ Wf, const float* __restrict__ bf,
    const float* __restrict__ wt1, const float* __restrict__ d1,
    const float* __restrict__ wt2, const float* __restrict__ d2,
    const float* __restrict__ wt3, const float* __restrict__ d3,
    const float* __restrict__ X, float* __restrict__ Xrec, float* __restrict__ lhood)
{
    __shared__ float zs[32];
    __shared__ float h1[64 * 36];      // 2304
    __shared__ float u2[16 * 324];     // 5184 ; sl (1088) aliased at front
    __shared__ float wt3s[256];
    __shared__ float sh4[4];
    float* sl = u2;
    float* h2 = u2;
    int bidx = blockIdx.x;
    int t = threadIdx.x;
    int w = t >> 6, l = t & 63;
    int py = w >> 1, px = w & 1;
    if (t < 32) zs[t] = ztL[(size_t)bidx * 64 + 32 + t];
    wt3s[t] = wt3[t];
    __syncthreads();

    // ---- fc3 ----
    {
        float4 acc = ((const float4*)bf)[t];
        const float4* Wf4 = (const float4*)Wf;
        #pragma unroll 4
        for (int q = 0; q < 32; q++) {
            float zq = zs[q];
            float4 wv = Wf4[q * 256 + t];
            acc.x = fmaf(zq, wv.x, acc.x);
            acc.y = fmaf(zq, wv.y, acc.y);
            acc.z = fmaf(zq, wv.z, acc.z);
            acc.w = fmaf(zq, wv.w, acc.w);
        }
        int k0 = t * 4;
        int ci = k0 >> 4, p0 = k0 & 15;
        sl[(p0+0) * 68 + ci] = acc.x;
        sl[(p0+1) * 68 + ci] = acc.y;
        sl[(p0+2) * 68 + ci] = acc.z;
        sl[(p0+3) * 68 + ci] = acc.w;
    }
    __syncthreads();

    // ---- deconv1: [4,4,64] -> [8,8,32]; thread = 2pos x 4oc ----
    {
        int ocq = l >> 3, pp = l & 7;
        int a_ = pp >> 1, b2 = pp & 1;
        float acc0[4], acc1[4];
        #pragma unroll
        for (int j = 0; j < 4; j++) { acc0[j] = d1[ocq * 4 + j]; acc1[j] = acc0[j]; }
        #pragma unroll
        for (int sy = 0; sy < 2; sy++) {
            int ky = py + 2 * sy;
            int iy = a_ + py + sy - 1;
            if ((unsigned)iy >= 4u) continue;
            #pragma unroll
            for (int sx = 0; sx < 2; sx++) {
                int kx = px + 2 * sx;
                int ix0 = 2 * b2 + px + sx - 1;
                int ix1 = ix0 + 1;
                bool v0 = (unsigned)ix0 < 4u, v1 = (unsigned)ix1 < 4u;
                const float4* ip0 = (const float4*)(sl + (iy * 4 + ix0) * 68);
                const float4* ip1 = (const float4*)(sl + (iy * 4 + ix1) * 68);
                const float* wb = wt1 + (ky * 4 + kx) * 2048 + ocq * 4;
                #pragma unroll 4
                for (int cc = 0; cc < 16; cc++) {
                    float4 va = v0 ? ip0[cc] : make_float4(0.f,0.f,0.f,0.f);
                    float4 vb = v1 ? ip1[cc] : make_float4(0.f,0.f,0.f,0.f);
                    float av[4] = {va.x, va.y, va.z, va.w};
                    float bv[4] = {vb.x, vb.y, vb.z, vb.w};
                    #pragma unroll
                    for (int r = 0; r < 4; r++) {
                        float4 wv = *(const float4*)(wb + (cc * 4 + r) * 32);
                        acc0[0] = fmaf(av[r], wv.x, acc0[0]); acc1[0] = fmaf(bv[r], wv.x, acc1[0]);
                        acc0[1] = fmaf(av[r], wv.y, acc0[1]); acc1[1] = fmaf(bv[r], wv.y, acc1[1]);
                        acc0[2] = fmaf(av[r], wv.z, acc0[2]); acc1[2] = fmaf(bv[r], wv.z, acc1[2]);
                        acc0[3] = fmaf(av[r], wv.w, acc0[3]); acc1[3] = fmaf(bv[r], wv.w, acc1[3]);
                    }
                }
            }
        }
        int oy = 2 * a_ + py;
        int ox0 = 4 * b2 + px, ox1 = ox0 + 2;
        float4 r0, r1;
        r0.x = fmaxf(acc0[0],0.f); r0.y = fmaxf(acc0[1],0.f); r0.z = fmaxf(acc0[2],0.f); r0.w = fmaxf(acc0[3],0.f);
        r1.x = fmaxf(acc1[0],0.f); r1.y = fmaxf(acc1[1],0.f); r1.z = fmaxf(acc1[2],0.f); r1.w = fmaxf(acc1[3],0.f);
        *(float4*)(h1 + (oy * 8 + ox0) * 36 + ocq * 4) = r0;
        *(float4*)(h1 + (oy * 8 + ox1) * 36 + ocq * 4) = r1;
    }
    __syncthreads();

    // ---- deconv2: [8,8,32] -> [16,16,16]; thread = 4pos x 4oc ----
    {
        int ocq = l >> 4, s = l & 15;
        int qa = s >> 2, qb = s & 3;
        float acc[4][4];
        #pragma unroll
        for (int u = 0; u < 4; u++)
            #pragma unroll
            for (int j = 0; j < 4; j++) acc[u][j] = d2[ocq * 4 + j];
        #pragma unroll
        for (int sy = 0; sy < 2; sy++) {
            int ky = py + 2 * sy;
            int iyb = 2 * qa + py + sy - 1;
            bool vy0 = (unsigned)iyb < 8u, vy1 = (unsigned)(iyb + 1) < 8u;
            #pragma unroll
            for (int sx = 0; sx < 2; sx++) {
                int kx = px + 2 * sx;
                int ixb = 2 * qb + px + sx - 1;
                bool vx0 = (unsigned)ixb < 8u, vx1 = (unsigned)(ixb + 1) < 8u;
                const float4* p00 = (const float4*)(h1 + (iyb * 8 + ixb) * 36);
                const float4* p01 = (const float4*)(h1 + (iyb * 8 + ixb + 1) * 36);
                const float4* p10 = (const float4*)(h1 + ((iyb + 1) * 8 + ixb) * 36);
                const float4* p11 = (const float4*)(h1 + ((iyb + 1) * 8 + ixb + 1) * 36);
                const float* wb = wt2 + (ky * 4 + kx) * 512 + ocq * 4;
                #pragma unroll 2
                for (int cc = 0; cc < 8; cc++) {
                    float4 v00 = (vy0 && vx0) ? p00[cc] : make_float4(0.f,0.f,0.f,0.f);
                    float4 v01 = (vy0 && vx1) ? p01[cc] : make_float4(0.f,0.f,0.f,0.f);
                    float4 v10 = (vy1 && vx0) ? p10[cc] : make_float4(0.f,0.f,0.f,0.f);
                    float4 v11 = (vy1 && vx1) ? p11[cc] : make_float4(0.f,0.f,0.f,0.f);
                    float m00[4] = {v00.x,v00.y,v00.z,v00.w};
                    float m01[4] = {v01.x,v01.y,v01.z,v01.w};
                    float m10[4] = {v10.x,v10.y,v10.z,v10.w};
                    float m11[4] = {v11.x,v11.y,v11.z,v11.w};
                    #pragma unroll
                    for (int r = 0; r < 4; r++) {
                        float4 wv = *(const float4*)(wb + (cc * 4 + r) * 16);
                        acc[0][0] = fmaf(m00[r], wv.x, acc[0][0]);
                        acc[0][1] = fmaf(m00[r], wv.y, acc[0][1]);
                        acc[0][2] = fmaf(m00[r], wv.z, acc[0][2]);
                        acc[0][3] = fmaf(m00[r], wv.w, acc[0][3]);
                        acc[1][0] = fmaf(m01[r], wv.x, acc[1][0]);
                        acc[1][1] = fmaf(m01[r], wv.y, acc[1][1]);
                        acc[1][2] = fmaf(m01[r], wv.z, acc[1][2]);
                        acc[1][3] = fmaf(m01[r], wv.w, acc[1][3]);
                        acc[2][0] = fmaf(m10[r], wv.x, acc[2][0]);
                        acc[2][1] = fmaf(m10[r], wv.y, acc[2][1]);
                        acc[2][2] = fmaf(m10[r], wv.z, acc[2][2]);
                        acc[2][3] = fmaf(m10[r], wv.w, acc[2][3]);
                        acc[3][0] = fmaf(m11[r], wv.x, acc[3][0]);
                        acc[3][1] = fmaf(m11[r], wv.y, acc[3][1]);
                        acc[3][2] = fmaf(m11[r], wv.z, acc[3][2]);
                        acc[3][3] = fmaf(m11[r], wv.w, acc[3][3]);
                    }
                }
            }
        }
        __syncthreads();   // sl reads done before h2 overwrite (alias!)
        #pragma unroll
        for (int u = 0; u < 2; u++) {
            #pragma unroll
            for (int v = 0; v < 2; v++) {
                int oy = 2 * (2 * qa + u) + py;
                int ox = 2 * (2 * qb + v) + px;
                float4 r;
                r.x = fmaxf(acc[u*2+v][0], 0.f);
                r.y = fmaxf(acc[u*2+v][1], 0.f);
                r.z = fmaxf(acc[u*2+v][2], 0.f);
                r.w = fmaxf(acc[u*2+v][3], 0.f);
                *(float4*)(h2 + oy * 324 + ox * 20 + ocq * 4) = r;
            }
        }
    }
    __syncthreads();

    // ---- deconv3: [16,16,16] -> [32,32], sigmoid, lhood ----
    {
        int a_ = l >> 2, bb = l & 3;
        float acc[4];
        float d30 = d3[0];
        #pragma unroll
        for (int k = 0; k < 4; k++) acc[k] = d30;
        #pragma unroll
        for (int sy = 0; sy < 2; sy++) {
            int ky = py + 2 * sy;
            int iy = a_ + py + sy - 1;
            if ((unsigned)iy >= 16u) continue;
            #pragma unroll
            for (int sx = 0; sx < 2; sx++) {
                int kx = px + 2 * sx;
                const float* wv = wt3s + (ky * 4 + kx) * 16;
                #pragma unroll
                for (int k = 0; k < 4; k++) {
                    int ix = bb + 4 * k + px + sx - 1;
                    if ((unsigned)ix >= 16u) continue;
                    const float4* in4 = (const float4*)(h2 + iy * 324 + ix * 20);
                    #pragma unroll
                    for (int cc = 0; cc < 4; cc++) {
                        float4 v = in4[cc];
                        float4 wq = ((const float4*)wv)[cc];
                        acc[k] = fmaf(v.x, wq.x, acc[k]);
                        acc[k] = fmaf(v.y, wq.y, acc[k]);
                        acc[k] = fmaf(v.z, wq.z, acc[k]);
                        acc[k] = fmaf(v.w, wq.w, acc[k]);
                    }
                }
            }
        }
        int oy = 2 * a_ + py;
        float ll = 0.f;
        #pragma unroll
        for (int k = 0; k < 4; k++) {
            int ox = 2 * (bb + 4 * k) + px;
            float xr = 1.f / (1.f + expf(-acc[k]));
            size_t oi = (size_t)bidx * 1024 + oy * 32 + ox;
            Xrec[oi] = xr;
            float xv = X[oi];
            ll += logf(0.001f + xr) * xv + logf(1.001f - xr) * (1.f - xv);
        }
        #pragma unroll
        for (int off = 32; off; off >>= 1) ll += __shfl_down(ll, off, 64);
        if ((t & 63) == 0) sh4[t >> 6] = ll;
    }
    __syncthreads();
    if (t == 0) atomicAdd(&lhood[bidx / T_S], sh4[0] + sh4[1] + sh4[2] + sh4[3]);
}

// ---------------- kl_z ----------------
__global__ __launch_bounds__(64) void klz_kernel(
    const float* __restrict__ ztL, const float* __restrict__ logp, float* __restrict__ klz)
{
    int n = blockIdx.x, t = threadIdx.x;
    float v = 0.f;
    if (t < T_S) {
        const float* z = ztL + ((size_t)n * T_S + t) * 64;
        float s2 = 0.f;
        #pragma unroll
        for (int j = 0; j < 64; j++) s2 = fmaf(z[j], z[j], s2);
        v = logp[n * T_S + t] - (-0.5f * s2 - Q_S * LOG2PI_F);
    }
    #pragma unroll
    for (int off = 32; off; off >>= 1) v += __shfl_down(v, off, 64);
    if (t == 0) klz[n] = v;
}

// ---------------- kl_w ----------------
__global__ __launch_bounds__(256) void klw_kernel(
    const float* __restrict__ W1, const float* __restrict__ W2, float* __restrict__ klw)
{
    __shared__ float sh4[4];
    int t = threadIdx.x;
    float a = 0.f;
    for (int i = t; i < 64 * HDYN_S; i += 256) a = fmaf(W1[i], W1[i], a);
    for (int i = t; i < HDYN_S * Q_S; i += 256) a = fmaf(W2[i], W2[i], a);
    #pragma unroll
    for (int off = 32; off; off >>= 1) a += __shfl_down(a, off, 64);
    if ((t & 63) == 0) sh4[t >> 6] = a;
    __syncthreads();
    if (t == 0) klw[0] = 0.5f * (sh4[0] + sh4[1] + sh4[2] + sh4[3]);
}

// ---------------- final scalars ----------------
__global__ __launch_bounds__(256) void final_kernel(
    const float* __restrict__ lhood, const float* __restrict__ klz,
    const float* __restrict__ klw, const int* __restrict__ Ndata,
    float* __restrict__ outs)
{
    __shared__ float shA[4], shB[4];
    int t = threadIdx.x;
    float a = lhood[t];
    float b = klz[t];
    #pragma unroll
    for (int off = 32; off; off >>= 1) {
        a += __shfl_down(a, off, 64);
        b += __shfl_down(b, off, 64);
    }
    if ((t & 63) == 0) { shA[t >> 6] = a; shB[t >> 6] = b; }
    __syncthreads();
    if (t == 0) {
        float Nd = (float)Ndata[0];
        float lh = Nd * ((shA[0] + shA[1] + shA[2] + shA[3]) / 256.f);
        float kz = Nd * ((shB[0] + shB[1] + shB[2] + shB[3]) / 256.f);
        float bkw = 1.0f * klw[0];
        outs[0] = lh - kz - bkw;
        outs[1] = lh;
        outs[2] = kz;
        outs[3] = bkw;
    }
}

extern "C" void kernel_launch(void* const* d_in, const int* in_sizes, int n_in,
                              void* d_out, int out_size, void* d_ws, size_t ws_size,
                              hipStream_t stream) {
    const float* X      = (const float*)d_in[0];
    const float* eps_s0 = (const float*)d_in[1];
    const float* eps_v0 = (const float*)d_in[2];
    const float* Cs1 = (const float*)d_in[3],  *cs1 = (const float*)d_in[4];
    const float* Cs2 = (const float*)d_in[5],  *cs2 = (const float*)d_in[6];
    const float* Cs3 = (const float*)d_in[7],  *cs3 = (const float*)d_in[8];
    const float* Wsm = (const float*)d_in[9],  *bsm = (const float*)d_in[10];
    const float* Wsl = (const float*)d_in[11], *bsl = (const float*)d_in[12];
    const float* Cv1 = (const float*)d_in[13], *cv1 = (const float*)d_in[14];
    const float* Cv2 = (const float*)d_in[15], *cv2 = (const float*)d_in[16];
    const float* Cv3 = (const float*)d_in[17], *cv3 = (const float*)d_in[18];
    const float* Wvm = (const float*)d_in[19], *bvm = (const float*)d_in[20];
    const float* Wvl = (const float*)d_in[21], *bvl = (const float*)d_in[22];
    const float* W1  = (const float*)d_in[23], *b1  = (const float*)d_in[24];
    const float* W2  = (const float*)d_in[25], *b2  = (const float*)d_in[26];
    const float* Wf  = (const float*)d_in[27], *bf  = (const float*)d_in[28];
    const float* D1  = (const float*)d_in[29], *d1  = (const float*)d_in[30];
    const float* D2  = (const float*)d_in[31], *d2  = (const float*)d_in[32];
    const float* D3  = (const float*)d_in[33], *d3  = (const float*)d_in[34];
    const int*   Ndata = (const int*)d_in[35];

    float* out = (float*)d_out;
    float* ws  = (float*)d_ws;

    zero_kernel<<<1, 256, 0, stream>>>(ws + WS_LHOOD, 256);
    prep_enc<<<331, 256, 0, stream>>>(Cs1, Cv1, Cs2, Cv2, Cs3, Cv3, ws);

    // ---- encoder s (frame 0) ----
    conv1_lds<1><<<256, 256, 0, stream>>>(X, ws + TC_S1, cs1, ws + WS_A1);
    conv2_lds<<<256, 256, 0, stream>>>(ws + WS_A1, ws + TC_S2, cs2, ws + WS_A2);
    conv3_lds<<<dim3(256, 2), 256, 0, stream>>>(ws + WS_A2, ws + TC_S3, cs3, ws + WS_A3);
    fc_enc2<<<256, 256, 0, stream>>>(ws + WS_A3, Wsm, bsm, Wsl, bsl, ws + WS_S0MU, ws + WS_S0LV);

    // ---- encoder v (10 frames as channels) ----
    conv1_lds<10><<<256, 256, 0, stream>>>(X, ws + TC_V1, cv1, ws + WS_A1);
    conv2_lds<<<256, 256, 0, stream>>>(ws + WS_A1, ws + TC_V2, cv2, ws + WS_A2);
    conv3_lds<<<dim3(256, 2), 256, 0, stream>>>(ws + WS_A2, ws + TC_V3, cv3, ws + WS_A3);
    fc_enc2<<<256, 256, 0, stream>>>(ws + WS_A3, Wvm, bvm, Wvl, bvl, ws + WS_V0MU, ws + WS_V0LV);

    // ---- reparameterize ----
    reparam_kernel<<<256, 64, 0, stream>>>(ws + WS_S0MU, ws + WS_S0LV, ws + WS_V0MU, ws + WS_V0LV,
                                           eps_s0, eps_v0,
                                           out + OUT_QM, out + OUT_QLV,
                                           out + OUT_ZT, ws + WS_LOGP);

    // ---- decoder weight transpose (A-regions now dead) ----
    prep_dec<<<161, 256, 0, stream>>>(D1, D2, D3, ws);

    // ---- RK4 ODE ----
    ode_kernel<<<256, 256, 0, stream>>>(W1, b1, W2, b2, out + OUT_ZT, ws + WS_LOGP);

    // ---- fused decoder ----
    decoder3<<<5120, 256, 0, stream>>>(out + OUT_ZT, Wf, bf,
                                       ws + WS_WT1, d1, ws + WS_WT2, d2, ws + WS_WT3, d3,
                                       X, out + OUT_XREC, ws + WS_LHOOD);

    // ---- ELBO pieces ----
    klz_kernel<<<256, 64, 0, stream>>>(out + OUT_ZT, ws + WS_LOGP, ws + WS_KLZ);
    klw_kernel<<<1, 256, 0, stream>>>(W1, W2, ws + WS_KLW);
    final_kernel<<<1, 256, 0, stream>>>(ws + WS_LHOOD, ws + WS_KLZ, ws + WS_KLW, Ndata,
                                        out + OUT_SCAL);
}

// Round 4
// 650.168 us; speedup vs baseline: 2.4398x; 1.5197x over previous
//
#include <hip/hip_runtime.h>
#include <math.h>

#define N_S 256
#define T_S 20
#define D_S 32
#define NF_S 16
#define Q_S 32
#define HDYN_S 256
#define HDIM_S 1024
#define VSTEPS_S 10
#define DT_S 0.1f
#define LOG2PI_F 1.8378770664093453f

// ---- d_out offsets (floats) ----
#define OUT_XREC 0
#define OUT_QM   5242880
#define OUT_QLV  5259264
#define OUT_ZT   5275648
#define OUT_SCAL 5603328

// ---- workspace offsets (floats) ----
#define WS_A1    0          // conv1 out [b][16][16][16] = 1,048,576
#define WS_A3    0          // conv3 out [b][64][4][4]   =   262,144 (A1 dead)
#define WS_WT1   0          // decoder: 32768  [tap][ci=64][co=32]
#define WS_WT2   32768      //          8192   [tap][ci=32][co=16]
#define WS_WT3   40960      //          256    [tap][ci=16]
#define WS_A2    1048576    // conv2 out [b][32][8][8] = 524,288
#define WS_S0MU  1572864
#define WS_S0LV  1581056
#define WS_V0MU  1589248
#define WS_V0LV  1597440
#define WS_LOGP  1605632
#define WS_LHOOD 1610752
#define WS_KLZ   1611008
#define WS_KLW   1611264
#define WS_TC    1611520    // encoder transposed weights [ci][tap][co]
#define TC_S1 (WS_TC + 0)
#define TC_V1 (WS_TC + 256)
#define TC_S2 (WS_TC + 2816)
#define TC_V2 (WS_TC + 11008)
#define TC_S3 (WS_TC + 19200)
#define TC_V3 (WS_TC + 51968)

__global__ __launch_bounds__(256) void zero_kernel(float* __restrict__ p, int n) {
    int i = blockIdx.x * 256 + threadIdx.x;
    if (i < n) p[i] = 0.f;
}

// ---------------- weight transposes ----------------
__device__ inline void enc_tr(const float* __restrict__ src, float* __restrict__ dst,
                              int e, int CI, int CO) {
    int co = e % CO; int r = e / CO; int tap = r & 15; int ci = r >> 4;
    dst[e] = src[(co * CI + ci) * 16 + tap];
}
__device__ inline void dec_tr(const float* __restrict__ src, float* __restrict__ dst,
                              int e, int CI, int CO) {
    int co = e % CO; int r = e / CO; int ci = r % CI; int tap = r / CI;
    dst[e] = src[(co * CI + ci) * 16 + tap];
}

__global__ __launch_bounds__(256) void prep_enc(
    const float* __restrict__ Cs1, const float* __restrict__ Cv1,
    const float* __restrict__ Cs2, const float* __restrict__ Cv2,
    const float* __restrict__ Cs3, const float* __restrict__ Cv3,
    float* __restrict__ ws)
{
    int idx = blockIdx.x * 256 + threadIdx.x;
    if (idx < 256)        enc_tr(Cs1, ws + TC_S1, idx,          1, 16);
    else if (idx < 2816)  enc_tr(Cv1, ws + TC_V1, idx - 256,   10, 16);
    else if (idx < 11008) enc_tr(Cs2, ws + TC_S2, idx - 2816,  16, 32);
    else if (idx < 19200) enc_tr(Cv2, ws + TC_V2, idx - 11008, 16, 32);
    else if (idx < 51968) enc_tr(Cs3, ws + TC_S3, idx - 19200, 32, 64);
    else if (idx < 84736) enc_tr(Cv3, ws + TC_V3, idx - 51968, 32, 64);
}

__global__ __launch_bounds__(256) void prep_dec(
    const float* __restrict__ D1, const float* __restrict__ D2,
    const float* __restrict__ D3, float* __restrict__ ws)
{
    int idx = blockIdx.x * 256 + threadIdx.x;
    if (idx < 32768)      dec_tr(D1, ws + WS_WT1, idx,         64, 32);
    else if (idx < 40960) dec_tr(D2, ws + WS_WT2, idx - 32768, 32, 16);
    else if (idx < 41216) dec_tr(D3, ws + WS_WT3, idx - 40960, 16, 1);
}

// ---------------- conv1 ----------------
template<int CIN>
__global__ __launch_bounds__(256) void conv1_lds(
    const float* __restrict__ x, const float* __restrict__ wt,
    const float* __restrict__ bias, float* __restrict__ out)
{
    __shared__ float xin[CIN * 1056];
    __shared__ float wl[CIN * 256];
    __shared__ float bl[16];
    int b = blockIdx.x, t = threadIdx.x;
    for (int e = t; e < CIN * 1024; e += 256) {
        int ci = e >> 10, r = e & 1023, iy = r >> 5, ix = r & 31;
        xin[ci * 1056 + iy * 33 + ix] = x[(size_t)b * 20480 + e];
    }
    for (int e = t; e < CIN * 256; e += 256) wl[e] = wt[e];
    if (t < 16) bl[t] = bias[t];
    __syncthreads();

    int ocq = t >> 7, p = t & 127;
    int oy = p >> 3, pb = p & 7;
    float acc0[8], acc1[8];
    #pragma unroll
    for (int j = 0; j < 8; j++) { acc0[j] = bl[ocq * 8 + j]; acc1[j] = acc0[j]; }
    for (int ci = 0; ci < CIN; ci++) {
        const float* xc = xin + ci * 1056;
        const float* wc = wl + ci * 256 + ocq * 8;
        #pragma unroll
        for (int ky = 0; ky < 4; ky++) {
            int iy = 2 * oy - 1 + ky;
            if ((unsigned)iy >= 32u) continue;
            const float* xr = xc + iy * 33;
            #pragma unroll
            for (int kx = 0; kx < 4; kx++) {
                int ix0 = 4 * pb - 1 + kx, ix1 = ix0 + 2;
                float v0 = ((unsigned)ix0 < 32u) ? xr[ix0] : 0.f;
                float v1 = ((unsigned)ix1 < 32u) ? xr[ix1] : 0.f;
                const float4* w4 = (const float4*)(wc + (ky * 4 + kx) * 16);
                float4 wa = w4[0], wb = w4[1];
                acc0[0] = fmaf(v0, wa.x, acc0[0]); acc1[0] = fmaf(v1, wa.x, acc1[0]);
                acc0[1] = fmaf(v0, wa.y, acc0[1]); acc1[1] = fmaf(v1, wa.y, acc1[1]);
                acc0[2] = fmaf(v0, wa.z, acc0[2]); acc1[2] = fmaf(v1, wa.z, acc1[2]);
                acc0[3] = fmaf(v0, wa.w, acc0[3]); acc1[3] = fmaf(v1, wa.w, acc1[3]);
                acc0[4] = fmaf(v0, wb.x, acc0[4]); acc1[4] = fmaf(v1, wb.x, acc1[4]);
                acc0[5] = fmaf(v0, wb.y, acc0[5]); acc1[5] = fmaf(v1, wb.y, acc1[5]);
                acc0[6] = fmaf(v0, wb.z, acc0[6]); acc1[6] = fmaf(v1, wb.z, acc1[6]);
                acc0[7] = fmaf(v0, wb.w, acc0[7]); acc1[7] = fmaf(v1, wb.w, acc1[7]);
            }
        }
    }
    size_t ob = (size_t)b * 4096 + (size_t)(ocq * 8) * 256 + oy * 16 + 2 * pb;
    #pragma unroll
    for (int j = 0; j < 8; j++) {
        float2 r; r.x = fmaxf(acc0[j], 0.f); r.y = fmaxf(acc1[j], 0.f);
        *(float2*)(out + ob + (size_t)j * 256) = r;
    }
}

// ---------------- conv2 ----------------
__global__ __launch_bounds__(256) void conv2_lds(
    const float* __restrict__ a1, const float* __restrict__ wt,
    const float* __restrict__ bias, float* __restrict__ out)
{
    __shared__ float xin[16 * 272];
    __shared__ float wl[8192];
    __shared__ float bl[32];
    int b = blockIdx.x, t = threadIdx.x;
    for (int e = t; e < 4096; e += 256) {
        int ci = e >> 8, r = e & 255, iy = r >> 4, ix = r & 15;
        xin[ci * 272 + iy * 17 + ix] = a1[(size_t)b * 4096 + e];
    }
    for (int e = t; e < 2048; e += 256) ((float4*)wl)[e] = ((const float4*)wt)[e];
    if (t < 32) bl[t] = bias[t];
    __syncthreads();

    int ocq = t >> 5, p = t & 31;
    int pa = p >> 2, pb = p & 3;
    float acc0[4], acc1[4];
    #pragma unroll
    for (int j = 0; j < 4; j++) { acc0[j] = bl[ocq * 4 + j]; acc1[j] = acc0[j]; }
    for (int ci = 0; ci < 16; ci++) {
        const float* xc = xin + ci * 272;
        const float* wc = wl + ci * 512 + ocq * 4;
        #pragma unroll
        for (int ky = 0; ky < 4; ky++) {
            int iy = 2 * pa - 1 + ky;
            if ((unsigned)iy >= 16u) continue;
            const float* xr = xc + iy * 17;
            #pragma unroll
            for (int kx = 0; kx < 4; kx++) {
                int ix0 = 4 * pb - 1 + kx, ix1 = ix0 + 2;
                float v0 = ((unsigned)ix0 < 16u) ? xr[ix0] : 0.f;
                float v1 = ((unsigned)ix1 < 16u) ? xr[ix1] : 0.f;
                float4 wv = *(const float4*)(wc + (ky * 4 + kx) * 32);
                acc0[0] = fmaf(v0, wv.x, acc0[0]); acc1[0] = fmaf(v1, wv.x, acc1[0]);
                acc0[1] = fmaf(v0, wv.y, acc0[1]); acc1[1] = fmaf(v1, wv.y, acc1[1]);
                acc0[2] = fmaf(v0, wv.z, acc0[2]); acc1[2] = fmaf(v1, wv.z, acc1[2]);
                acc0[3] = fmaf(v0, wv.w, acc0[3]); acc1[3] = fmaf(v1, wv.w, acc1[3]);
            }
        }
    }
    size_t ob = (size_t)b * 2048 + (size_t)(ocq * 4) * 64 + pa * 8 + 2 * pb;
    #pragma unroll
    for (int j = 0; j < 4; j++) {
        float2 r; r.x = fmaxf(acc0[j], 0.f); r.y = fmaxf(acc1[j], 0.f);
        *(float2*)(out + ob + (size_t)j * 64) = r;
    }
}

// ---------------- conv3 ----------------
__global__ __launch_bounds__(256) void conv3_lds(
    const float* __restrict__ a2, const float* __restrict__ wt,
    const float* __restrict__ bias, float* __restrict__ out)
{
    __shared__ float xin[32 * 72];
    __shared__ float wl[16384];
    __shared__ float bl[32];
    int b = blockIdx.x, h = blockIdx.y, t = threadIdx.x;
    for (int e = t; e < 2048; e += 256) {
        int ci = e >> 6, r = e & 63, iy = r >> 3, ix = r & 7;
        xin[ci * 72 + iy * 9 + ix] = a2[(size_t)b * 2048 + e];
    }
    for (int e4 = t; e4 < 4096; e4 += 256) {
        int grp = e4 >> 3, c4 = e4 & 7;
        ((float4*)wl)[e4] = ((const float4*)(wt + grp * 64 + h * 32))[c4];
    }
    if (t < 32) bl[t] = bias[h * 32 + t];
    __syncthreads();

    int ocq = t >> 4, p = t & 15;
    int pa = p >> 2, pb = p & 3;
    float a0 = bl[ocq * 2], a1 = bl[ocq * 2 + 1];
    for (int ci = 0; ci < 32; ci++) {
        const float* xc = xin + ci * 72;
        const float* wc = wl + ci * 512 + ocq * 2;
        #pragma unroll
        for (int ky = 0; ky < 4; ky++) {
            int iy = 2 * pa - 1 + ky;
            if ((unsigned)iy >= 8u) continue;
            const float* xr = xc + iy * 9;
            #pragma unroll
            for (int kx = 0; kx < 4; kx++) {
                int ix = 2 * pb - 1 + kx;
                if ((unsigned)ix >= 8u) continue;
                float v = xr[ix];
                float2 wv = *(const float2*)(wc + (ky * 4 + kx) * 32);
                a0 = fmaf(v, wv.x, a0);
                a1 = fmaf(v, wv.y, a1);
            }
        }
    }
    size_t ob = (size_t)b * 1024 + (size_t)(h * 32 + ocq * 2) * 16 + pa * 4 + pb;
    out[ob] = fmaxf(a0, 0.f);
    out[ob + 16] = fmaxf(a1, 0.f);
}

// ---------------- encoder fc ----------------
__global__ __launch_bounds__(256) void fc_enc2(
    const float* __restrict__ h,
    const float* __restrict__ Wm, const float* __restrict__ bm,
    const float* __restrict__ Wl, const float* __restrict__ bl,
    float* __restrict__ mu, float* __restrict__ lv)
{
    __shared__ float pm[8][32], pl[8][32];
    int b = blockIdx.x, t = threadIdx.x;
    int q = t & 31, c = t >> 5;
    const float* hb = h + (size_t)b * HDIM_S + c * 128;
    const float* wmp = Wm + (c * 128) * Q_S + q;
    const float* wlp = Wl + (c * 128) * Q_S + q;
    float am = 0.f, al = 0.f;
    #pragma unroll 4
    for (int k = 0; k < 128; k++) {
        float hv = hb[k];
        am = fmaf(hv, wmp[k * Q_S], am);
        al = fmaf(hv, wlp[k * Q_S], al);
    }
    pm[c][q] = am; pl[c][q] = al;
    __syncthreads();
    if (t < 32) {
        float s = bm[t];
        #pragma unroll
        for (int c2 = 0; c2 < 8; c2++) s += pm[c2][t];
        mu[b * Q_S + t] = s;
    } else if (t < 64) {
        int qq = t - 32;
        float s = bl[qq];
        #pragma unroll
        for (int c2 = 0; c2 < 8; c2++) s += pl[c2][qq];
        lv[b * Q_S + qq] = s;
    }
}

// ---------------- reparameterize ----------------
__global__ __launch_bounds__(64) void reparam_kernel(
    const float* __restrict__ s0mu, const float* __restrict__ s0lv,
    const float* __restrict__ v0mu, const float* __restrict__ v0lv,
    const float* __restrict__ eps_s, const float* __restrict__ eps_v,
    float* __restrict__ qm, float* __restrict__ qlv,
    float* __restrict__ ztL, float* __restrict__ logp)
{
    int n = blockIdx.x, t = threadIdx.x;
    int q = t & 31;
    float mu, lvv, ep;
    if (t < 32) { mu = v0mu[n*32+q]; lvv = v0lv[n*32+q]; ep = eps_v[n*32+q]; }
    else        { mu = s0mu[n*32+q]; lvv = s0lv[n*32+q]; ep = eps_s[n*32+q]; }
    float zv = fmaf(ep, expf(lvv), mu);
    qm[n*64 + t]  = mu;
    qlv[n*64 + t] = lvv;
    ztL[(size_t)n * T_S * 64 + t] = zv;
    float e2 = ep * ep;
    #pragma unroll
    for (int off = 32; off; off >>= 1) e2 += __shfl_down(e2, off, 64);
    if (t == 0) logp[n * T_S] = -0.5f * e2 - Q_S * LOG2PI_F;
}

// ---------------- RK4 ODE ----------------
__global__ __launch_bounds__(256) void ode_kernel(
    const float* __restrict__ W1, const float* __restrict__ b1,
    const float* __restrict__ W2, const float* __restrict__ b2,
    float* __restrict__ ztL, float* __restrict__ logp)
{
    __shared__ float W2s[HDYN_S * Q_S];
    __shared__ float zeval[64];
    __shared__ float hsh[HDYN_S];
    __shared__ float dvred[HDYN_S];
    __shared__ float red4[4];
    int n = blockIdx.x;
    int t = threadIdx.x;

    for (int i = t; i < HDYN_S * Q_S; i += 256) W2s[i] = W2[i];
    float w1r[64];
    #pragma unroll
    for (int j = 0; j < 64; j++) w1r[j] = W1[j * HDYN_S + t];
    float b1r = b1[t];
    __syncthreads();
    float ck = 0.f;
    #pragma unroll
    for (int i = 0; i < Q_S; i++) ck = fmaf(w1r[i], W2s[t * Q_S + i], ck);

    size_t zoff = (size_t)n * T_S * 64;
    float zj = 0.f, ksumj = 0.f, zevalj = 0.f, lp = 0.f, lsum = 0.f;
    if (t < 64) { zj = ztL[zoff + t]; zevalj = zj; zeval[t] = zj; }
    if (t == 0) lp = logp[n * T_S];

    const float wc[4] = {1.f, 2.f, 2.f, 1.f};
    const float ac[3] = {0.5f * DT_S, 0.5f * DT_S, DT_S};

    for (int step = 1; step < T_S; step++) {
        for (int e = 0; e < 4; e++) {
            __syncthreads();
            float pre = b1r;
            #pragma unroll
            for (int j = 0; j < 64; j++) pre = fmaf(zeval[j], w1r[j], pre);
            float hk = tanhf(pre);
            hsh[t] = hk;
            float gk = (1.f - hk * hk) * ck;
            #pragma unroll
            for (int off = 32; off; off >>= 1) gk += __shfl_down(gk, off, 64);
            if ((t & 63) == 0) red4[t >> 6] = gk;
            __syncthreads();
            {
                int i = t & 31, p = t >> 5;
                float a = 0.f;
                #pragma unroll
                for (int kk = 0; kk < 32; kk++)
                    a = fmaf(hsh[p * 32 + kk], W2s[(p * 32 + kk) * Q_S + i], a);
                dvred[t] = a;
            }
            __syncthreads();
            if (t < 64) {
                float tr = red4[0] + red4[1] + red4[2] + red4[3];
                float zv_shfl = __shfl(zevalj, (t >= 32) ? (t - 32) : t, 64);
                float kzv;
                if (t < 32) {
                    float dvi = b2[t];
                    #pragma unroll
                    for (int p = 0; p < 8; p++) dvi += dvred[p * 32 + t];
                    kzv = dvi;
                } else kzv = zv_shfl;
                if (e == 0) ksumj = kzv; else ksumj = fmaf(wc[e], kzv, ksumj);
                if (t == 0) { float kl = -tr; lsum = (e == 0) ? kl : fmaf(wc[e], kl, lsum); }
                if (e < 3) {
                    zevalj = fmaf(ac[e], kzv, zj);
                    zeval[t] = zevalj;
                } else {
                    zj = fmaf(DT_S / 6.f, ksumj, zj);
                    zevalj = zj; zeval[t] = zj;
                    ztL[zoff + step * 64 + t] = zj;
                    if (t == 0) { lp = fmaf(DT_S / 6.f, lsum, lp); logp[n * T_S + step] = lp; }
                }
            }
        }
    }
}

// ---------------- fused decoder v4: parity-split LDS, coalesced I/O ----------------
// h1p: 4 planes [(py,px)] x 16 pos2 x 36 (stride 9u, odd)
// h2p: 4 planes x [ly stride 164 (41u odd)][lx stride 20 (5u odd)][16ci]
// sl : 16 pos x 68 (17u odd), aliased at front of h2p
// xst: 32 rows x 36 (9u odd), aliased onto h1p
__global__ __launch_bounds__(256) void decoder4(
    const float* __restrict__ ztL, const float* __restrict__ Wf, const float* __restrict__ bf,
    const float* __restrict__ wt1, const float* __restrict__ d1,
    const float* __restrict__ wt2, const float* __restrict__ d2,
    const float* __restrict__ wt3, const float* __restrict__ d3,
    const float* __restrict__ X, float* __restrict__ Xrec, float* __restrict__ lhood)
{
    __shared__ float zs[32];
    __shared__ float h1p[2304];
    __shared__ float u2[5248];
    __shared__ float wt3s[256];
    __shared__ float sh4[4];
    float* sl  = u2;
    float* h2p = u2;
    float* xst = h1p;
    const int bidx = blockIdx.x;
    const int t = threadIdx.x;
    const int w = t >> 6, l = t & 63;
    const int py = w >> 1, px = w & 1;
    if (t < 32) zs[t] = ztL[(size_t)bidx * 64 + 32 + t];
    wt3s[t] = wt3[t];
    __syncthreads();

    // ---- fc3: s = z_s @ Wf + bf -> sl[pos][ci] ----
    {
        float4 acc = ((const float4*)bf)[t];
        const float4* Wf4 = (const float4*)Wf;
        #pragma unroll 4
        for (int q = 0; q < 32; q++) {
            float zq = zs[q];
            float4 wv = Wf4[q * 256 + t];
            acc.x = fmaf(zq, wv.x, acc.x);
            acc.y = fmaf(zq, wv.y, acc.y);
            acc.z = fmaf(zq, wv.z, acc.z);
            acc.w = fmaf(zq, wv.w, acc.w);
        }
        int k0 = t * 4;
        int ci = k0 >> 4, p0 = k0 & 15;
        sl[(p0+0) * 68 + ci] = acc.x;
        sl[(p0+1) * 68 + ci] = acc.y;
        sl[(p0+2) * 68 + ci] = acc.z;
        sl[(p0+3) * 68 + ci] = acc.w;
    }
    __syncthreads();

    // ---- deconv1: [4,4,64] -> parity planes of [8,8,32]; thread = 2pos x 4oc ----
    {
        int ocq = l >> 3;                 // 0..7 -> oc = ocq*4
        int pp = l & 7;
        int a_ = pp >> 1, b2 = pp & 1;    // oy2 = a_, ox2 in {2b2, 2b2+1}
        float acc0[4], acc1[4];
        #pragma unroll
        for (int j = 0; j < 4; j++) { acc0[j] = d1[ocq * 4 + j]; acc1[j] = acc0[j]; }
        #pragma unroll
        for (int sy = 0; sy < 2; sy++) {
            int ky = py + 2 * sy;
            int iy = a_ + py + sy - 1;
            if ((unsigned)iy >= 4u) continue;
            #pragma unroll
            for (int sx = 0; sx < 2; sx++) {
                int kx = px + 2 * sx;
                int ix0 = 2 * b2 + px + sx - 1;
                int ix1 = ix0 + 1;
                bool v0 = (unsigned)ix0 < 4u, v1 = (unsigned)ix1 < 4u;
                const float4* ip0 = (const float4*)(sl + (iy * 4 + ix0) * 68);
                const float4* ip1 = (const float4*)(sl + (iy * 4 + ix1) * 68);
                const float* wb = wt1 + (ky * 4 + kx) * 2048 + ocq * 4;
                #pragma unroll 4
                for (int cc = 0; cc < 16; cc++) {
                    float4 va = v0 ? ip0[cc] : make_float4(0.f,0.f,0.f,0.f);
                    float4 vb = v1 ? ip1[cc] : make_float4(0.f,0.f,0.f,0.f);
                    float av[4] = {va.x, va.y, va.z, va.w};
                    float bv[4] = {vb.x, vb.y, vb.z, vb.w};
                    #pragma unroll
                    for (int r = 0; r < 4; r++) {
                        float4 wv = *(const float4*)(wb + (cc * 4 + r) * 32);
                        acc0[0] = fmaf(av[r], wv.x, acc0[0]); acc1[0] = fmaf(bv[r], wv.x, acc1[0]);
                        acc0[1] = fmaf(av[r], wv.y, acc0[1]); acc1[1] = fmaf(bv[r], wv.y, acc1[1]);
                        acc0[2] = fmaf(av[r], wv.z, acc0[2]); acc1[2] = fmaf(bv[r], wv.z, acc1[2]);
                        acc0[3] = fmaf(av[r], wv.w, acc0[3]); acc1[3] = fmaf(bv[r], wv.w, acc1[3]);
                    }
                }
            }
        }
        float* hp = h1p + (py * 2 + px) * 576;
        float4 r0, r1;
        r0.x = fmaxf(acc0[0],0.f); r0.y = fmaxf(acc0[1],0.f); r0.z = fmaxf(acc0[2],0.f); r0.w = fmaxf(acc0[3],0.f);
        r1.x = fmaxf(acc1[0],0.f); r1.y = fmaxf(acc1[1],0.f); r1.z = fmaxf(acc1[2],0.f); r1.w = fmaxf(acc1[3],0.f);
        *(float4*)(hp + (a_ * 4 + 2 * b2)     * 36 + ocq * 4) = r0;
        *(float4*)(hp + (a_ * 4 + 2 * b2 + 1) * 36 + ocq * 4) = r1;
    }
    __syncthreads();

    // ---- deconv2: parity [8,8,32] -> parity planes of [16,16,16]; thread = 4pos x 4oc ----
    {
        int ocq = l >> 4;                 // 0..3 -> oc = ocq*4
        int s = l & 15;
        int qa = s >> 2, qb = s & 3;      // out local iy2 in {2qa,2qa+1}, ix2 in {2qb,2qb+1}
        float acc[4][4];
        #pragma unroll
        for (int u = 0; u < 4; u++)
            #pragma unroll
            for (int j = 0; j < 4; j++) acc[u][j] = d2[ocq * 4 + j];
        #pragma unroll
        for (int sy = 0; sy < 2; sy++) {
            int ky = py + 2 * sy;
            int cy = py + sy - 1;
            int pA = cy & 1;  int lyA = qa + ((cy - pA) >> 1);
            int cy1 = cy + 1;
            int pB = cy1 & 1; int lyB = qa + ((cy1 - pB) >> 1);
            bool vyA = (unsigned)lyA < 4u, vyB = (unsigned)lyB < 4u;
            #pragma unroll
            for (int sx = 0; sx < 2; sx++) {
                int kx = px + 2 * sx;
                int cx = px + sx - 1;
                int pC = cx & 1;  int lxA = qb + ((cx - pC) >> 1);
                int cx1 = cx + 1;
                int pD = cx1 & 1; int lxB = qb + ((cx1 - pD) >> 1);
                bool vxA = (unsigned)lxA < 4u, vxB = (unsigned)lxB < 4u;
                const float4* p00 = (const float4*)(h1p + (pA*2+pC)*576 + (lyA*4+lxA)*36);
                const float4* p01 = (const float4*)(h1p + (pA*2+pD)*576 + (lyA*4+lxB)*36);
                const float4* p10 = (const float4*)(h1p + (pB*2+pC)*576 + (lyB*4+lxA)*36);
                const float4* p11 = (const float4*)(h1p + (pB*2+pD)*576 + (lyB*4+lxB)*36);
                bool g00 = vyA && vxA, g01 = vyA && vxB, g10 = vyB && vxA, g11 = vyB && vxB;
                const float* wb = wt2 + (ky * 4 + kx) * 512 + ocq * 4;
                #pragma unroll 2
                for (int cc = 0; cc < 8; cc++) {
                    float4 v00 = g00 ? p00[cc] : make_float4(0.f,0.f,0.f,0.f);
                    float4 v01 = g01 ? p01[cc] : make_float4(0.f,0.f,0.f,0.f);
                    float4 v10 = g10 ? p10[cc] : make_float4(0.f,0.f,0.f,0.f);
                    float4 v11 = g11 ? p11[cc] : make_float4(0.f,0.f,0.f,0.f);
                    float m00[4] = {v00.x,v00.y,v00.z,v00.w};
                    float m01[4] = {v01.x,v01.y,v01.z,v01.w};
                    float m10[4] = {v10.x,v10.y,v10.z,v10.w};
                    float m11[4] = {v11.x,v11.y,v11.z,v11.w};
                    #pragma unroll
                    for (int r = 0; r < 4; r++) {
                        float4 wv = *(const float4*)(wb + (cc * 4 + r) * 16);
                        acc[0][0] = fmaf(m00[r], wv.x, acc[0][0]);
                        acc[0][1] = fmaf(m00[r], wv.y, acc[0][1]);
                        acc[0][2] = fmaf(m00[r], wv.z, acc[0][2]);
                        acc[0][3] = fmaf(m00[r], wv.w, acc[0][3]);
                        acc[1][0] = fmaf(m01[r], wv.x, acc[1][0]);
                        acc[1][1] = fmaf(m01[r], wv.y, acc[1][1]);
                        acc[1][2] = fmaf(m01[r], wv.z, acc[1][2]);
                        acc[1][3] = fmaf(m01[r], wv.w, acc[1][3]);
                        acc[2][0] = fmaf(m10[r], wv.x, acc[2][0]);
                        acc[2][1] = fmaf(m10[r], wv.y, acc[2][1]);
                        acc[2][2] = fmaf(m10[r], wv.z, acc[2][2]);
                        acc[2][3] = fmaf(m10[r], wv.w, acc[2][3]);
                        acc[3][0] = fmaf(m11[r], wv.x, acc[3][0]);
                        acc[3][1] = fmaf(m11[r], wv.y, acc[3][1]);
                        acc[3][2] = fmaf(m11[r], wv.z, acc[3][2]);
                        acc[3][3] = fmaf(m11[r], wv.w, acc[3][3]);
                    }
                }
            }
        }
        float* hq = h2p + (py * 2 + px) * 1312;
        #pragma unroll
        for (int u = 0; u < 2; u++) {
            #pragma unroll
            for (int v = 0; v < 2; v++) {
                float4 r;
                r.x = fmaxf(acc[u*2+v][0], 0.f);
                r.y = fmaxf(acc[u*2+v][1], 0.f);
                r.z = fmaxf(acc[u*2+v][2], 0.f);
                r.w = fmaxf(acc[u*2+v][3], 0.f);
                *(float4*)(hq + (2*qa+u) * 164 + (2*qb+v) * 20 + ocq * 4) = r;
            }
        }
    }
    __syncthreads();

    // ---- deconv3: parity [16,16,16] -> [32,32] staged in LDS ----
    {
        int oy2 = l >> 2, b3 = l & 3;
        float acc[4];
        float d30 = d3[0];
        #pragma unroll
        for (int k = 0; k < 4; k++) acc[k] = d30;
        #pragma unroll
        for (int sy = 0; sy < 2; sy++) {
            int ky = py + 2 * sy;
            int iy = oy2 + py + sy - 1;
            if ((unsigned)iy >= 16u) continue;
            int pyi = iy & 1, ly = iy >> 1;
            #pragma unroll
            for (int sx = 0; sx < 2; sx++) {
                int kx = px + 2 * sx;
                int cx = px + sx - 1;
                const float* wv = wt3s + (ky * 4 + kx) * 16;
                #pragma unroll
                for (int k = 0; k < 4; k++) {
                    int ix = b3 + 4 * k + cx;
                    if ((unsigned)ix >= 16u) continue;
                    int pxi = ix & 1, lx = ix >> 1;
                    const float4* in4 = (const float4*)(h2p + (pyi*2+pxi)*1312 + ly*164 + lx*20);
                    #pragma unroll
                    for (int cc = 0; cc < 4; cc++) {
                        float4 v = in4[cc];
                        float4 wq = ((const float4*)wv)[cc];
                        acc[k] = fmaf(v.x, wq.x, acc[k]);
                        acc[k] = fmaf(v.y, wq.y, acc[k]);
                        acc[k] = fmaf(v.z, wq.z, acc[k]);
                        acc[k] = fmaf(v.w, wq.w, acc[k]);
                    }
                }
            }
        }
        int oy = 2 * oy2 + py;
        #pragma unroll
        for (int k = 0; k < 4; k++) {
            int ox = 2 * (b3 + 4 * k) + px;
            xst[oy * 36 + ox] = 1.f / (1.f + expf(-acc[k]));
        }
    }
    __syncthreads();

    // ---- coalesced Xrec write + X read + lhood ----
    {
        int row = t >> 3, col = (t & 7) * 4;
        float4 xr4 = *(const float4*)(xst + row * 36 + col);
        *(float4*)(Xrec + (size_t)bidx * 1024 + t * 4) = xr4;
        float4 xi4 = *(const float4*)(X + (size_t)bidx * 1024 + t * 4);
        float ll = 0.f;
        ll += logf(0.001f + xr4.x) * xi4.x + logf(1.001f - xr4.x) * (1.f - xi4.x);
        ll += logf(0.001f + xr4.y) * xi4.y + logf(1.001f - xr4.y) * (1.f - xi4.y);
        ll += logf(0.001f + xr4.z) * xi4.z + logf(1.001f - xr4.z) * (1.f - xi4.z);
        ll += logf(0.001f + xr4.w) * xi4.w + logf(1.001f - xr4.w) * (1.f - xi4.w);
        #pragma unroll
        for (int off = 32; off; off >>= 1) ll += __shfl_down(ll, off, 64);
        if ((t & 63) == 0) sh4[t >> 6] = ll;
    }
    __syncthreads();
    if (t == 0) atomicAdd(&lhood[bidx / T_S], sh4[0] + sh4[1] + sh4[2] + sh4[3]);
}

// ---------------- kl_z ----------------
__global__ __launch_bounds__(64) void klz_kernel(
    const float* __restrict__ ztL, const float* __restrict__ logp, float* __restrict__ klz)
{
    int n = blockIdx.x, t = threadIdx.x;
    float v = 0.f;
    if (t < T_S) {
        const float* z = ztL + ((size_t)n * T_S + t) * 64;
        float s2 = 0.f;
        #pragma unroll
        for (int j = 0; j < 64; j++) s2 = fmaf(z[j], z[j], s2);
        v = logp[n * T_S + t] - (-0.5f * s2 - Q_S * LOG2PI_F);
    }
    #pragma unroll
    for (int off = 32; off; off >>= 1) v += __shfl_down(v, off, 64);
    if (t == 0) klz[n] = v;
}

// ---------------- kl_w ----------------
__global__ __launch_bounds__(256) void klw_kernel(
    const float* __restrict__ W1, const float* __restrict__ W2, float* __restrict__ klw)
{
    __shared__ float sh4[4];
    int t = threadIdx.x;
    float a = 0.f;
    for (int i = t; i < 64 * HDYN_S; i += 256) a = fmaf(W1[i], W1[i], a);
    for (int i = t; i < HDYN_S * Q_S; i += 256) a = fmaf(W2[i], W2[i], a);
    #pragma unroll
    for (int off = 32; off; off >>= 1) a += __shfl_down(a, off, 64);
    if ((t & 63) == 0) sh4[t >> 6] = a;
    __syncthreads();
    if (t == 0) klw[0] = 0.5f * (sh4[0] + sh4[1] + sh4[2] + sh4[3]);
}

// ---------------- final scalars ----------------
__global__ __launch_bounds__(256) void final_kernel(
    const float* __restrict__ lhood, const float* __restrict__ klz,
    const float* __restrict__ klw, const int* __restrict__ Ndata,
    float* __restrict__ outs)
{
    __shared__ float shA[4], shB[4];
    int t = threadIdx.x;
    float a = lhood[t];
    float b = klz[t];
    #pragma unroll
    for (int off = 32; off; off >>= 1) {
        a += __shfl_down(a, off, 64);
        b += __shfl_down(b, off, 64);
    }
    if ((t & 63) == 0) { shA[t >> 6] = a; shB[t >> 6] = b; }
    __syncthreads();
    if (t == 0) {
        float Nd = (float)Ndata[0];
        float lh = Nd * ((shA[0] + shA[1] + shA[2] + shA[3]) / 256.f);
        float kz = Nd * ((shB[0] + shB[1] + shB[2] + shB[3]) / 256.f);
        float bkw = 1.0f * klw[0];
        outs[0] = lh - kz - bkw;
        outs[1] = lh;
        outs[2] = kz;
        outs[3] = bkw;
    }
}

extern "C" void kernel_launch(void* const* d_in, const int* in_sizes, int n_in,
                              void* d_out, int out_size, void* d_ws, size_t ws_size,
                              hipStream_t stream) {
    const float* X      = (const float*)d_in[0];
    const float* eps_s0 = (const float*)d_in[1];
    const float* eps_v0 = (const float*)d_in[2];
    const float* Cs1 = (const float*)d_in[3],  *cs1 = (const float*)d_in[4];
    const float* Cs2 = (const float*)d_in[5],  *cs2 = (const float*)d_in[6];
    const float* Cs3 = (const float*)d_in[7],  *cs3 = (const float*)d_in[8];
    const float* Wsm = (const float*)d_in[9],  *bsm = (const float*)d_in[10];
    const float* Wsl = (const float*)d_in[11], *bsl = (const float*)d_in[12];
    const float* Cv1 = (const float*)d_in[13], *cv1 = (const float*)d_in[14];
    const float* Cv2 = (const float*)d_in[15], *cv2 = (const float*)d_in[16];
    const float* Cv3 = (const float*)d_in[17], *cv3 = (const float*)d_in[18];
    const float* Wvm = (const float*)d_in[19], *bvm = (const float*)d_in[20];
    const float* Wvl = (const float*)d_in[21], *bvl = (const float*)d_in[22];
    const float* W1  = (const float*)d_in[23], *b1  = (const float*)d_in[24];
    const float* W2  = (const float*)d_in[25], *b2  = (const float*)d_in[26];
    const float* Wf  = (const float*)d_in[27], *bf  = (const float*)d_in[28];
    const float* D1  = (const float*)d_in[29], *d1  = (const float*)d_in[30];
    const float* D2  = (const float*)d_in[31], *d2  = (const float*)d_in[32];
    const float* D3  = (const float*)d_in[33], *d3  = (const float*)d_in[34];
    const int*   Ndata = (const int*)d_in[35];

    float* out = (float*)d_out;
    float* ws  = (float*)d_ws;

    zero_kernel<<<1, 256, 0, stream>>>(ws + WS_LHOOD, 256);
    prep_enc<<<331, 256, 0, stream>>>(Cs1, Cv1, Cs2, Cv2, Cs3, Cv3, ws);

    // ---- encoder s (frame 0) ----
    conv1_lds<1><<<256, 256, 0, stream>>>(X, ws + TC_S1, cs1, ws + WS_A1);
    conv2_lds<<<256, 256, 0, stream>>>(ws + WS_A1, ws + TC_S2, cs2, ws + WS_A2);
    conv3_lds<<<dim3(256, 2), 256, 0, stream>>>(ws + WS_A2, ws + TC_S3, cs3, ws + WS_A3);
    fc_enc2<<<256, 256, 0, stream>>>(ws + WS_A3, Wsm, bsm, Wsl, bsl, ws + WS_S0MU, ws + WS_S0LV);

    // ---- encoder v (10 frames as channels) ----
    conv1_lds<10><<<256, 256, 0, stream>>>(X, ws + TC_V1, cv1, ws + WS_A1);
    conv2_lds<<<256, 256, 0, stream>>>(ws + WS_A1, ws + TC_V2, cv2, ws + WS_A2);
    conv3_lds<<<dim3(256, 2), 256, 0, stream>>>(ws + WS_A2, ws + TC_V3, cv3, ws + WS_A3);
    fc_enc2<<<256, 256, 0, stream>>>(ws + WS_A3, Wvm, bvm, Wvl, bvl, ws + WS_V0MU, ws + WS_V0LV);

    // ---- reparameterize ----
    reparam_kernel<<<256, 64, 0, stream>>>(ws + WS_S0MU, ws + WS_S0LV, ws + WS_V0MU, ws + WS_V0LV,
                                           eps_s0, eps_v0,
                                           out + OUT_QM, out + OUT_QLV,
                                           out + OUT_ZT, ws + WS_LOGP);

    // ---- decoder weight transpose (A-regions now dead) ----
    prep_dec<<<161, 256, 0, stream>>>(D1, D2, D3, ws);

    // ---- RK4 ODE ----
    ode_kernel<<<256, 256, 0, stream>>>(W1, b1, W2, b2, out + OUT_ZT, ws + WS_LOGP);

    // ---- fused decoder ----
    decoder4<<<5120, 256, 0, stream>>>(out + OUT_ZT, Wf, bf,
                                       ws + WS_WT1, d1, ws + WS_WT2, d2, ws + WS_WT3, d3,
                                       X, out + OUT_XREC, ws + WS_LHOOD);

    // ---- ELBO pieces ----
    klz_kernel<<<256, 64, 0, stream>>>(out + OUT_ZT, ws + WS_LOGP, ws + WS_KLZ);
    klw_kernel<<<1, 256, 0, stream>>>(W1, W2, ws + WS_KLW);
    final_kernel<<<1, 256, 0, stream>>>(ws + WS_LHOOD, ws + WS_KLZ, ws + WS_KLW, Ndata,
                                        out + OUT_SCAL);
}

// Round 5
// 583.269 us; speedup vs baseline: 2.7197x; 1.1147x over previous
//
#include <hip/hip_runtime.h>
#include <math.h>

#define N_S 256
#define T_S 20
#define D_S 32
#define NF_S 16
#define Q_S 32
#define HDYN_S 256
#define HDIM_S 1024
#define VSTEPS_S 10
#define DT_S 0.1f
#define LOG2PI_F 1.8378770664093453f

// ---- d_out offsets (floats) ----
#define OUT_XREC 0
#define OUT_QM   5242880
#define OUT_QLV  5259264
#define OUT_ZT   5275648
#define OUT_SCAL 5603328

// ---- workspace offsets (floats) ----
#define WS_A1    0
#define WS_A3    0
#define WS_WT1   0          // 32768  [tap][ci=64][co=32]
#define WS_WT2   32768      // 8192   [tap][ci=32][co=16]
#define WS_WT3   40960      // 256    [tap][ci=16]
#define WS_A2    1048576
#define WS_S0MU  1572864
#define WS_S0LV  1581056
#define WS_V0MU  1589248
#define WS_V0LV  1597440
#define WS_LOGP  1605632
#define WS_LHOOD 1610752
#define WS_KLZ   1611008
#define WS_KLW   1611264
#define WS_TC    1611520
#define TC_S1 (WS_TC + 0)
#define TC_V1 (WS_TC + 256)
#define TC_S2 (WS_TC + 2816)
#define TC_V2 (WS_TC + 11008)
#define TC_S3 (WS_TC + 19200)
#define TC_V3 (WS_TC + 51968)

// ---------------- weight transposes ----------------
__device__ inline void enc_tr(const float* __restrict__ src, float* __restrict__ dst,
                              int e, int CI, int CO) {
    int co = e % CO; int r = e / CO; int tap = r & 15; int ci = r >> 4;
    dst[e] = src[(co * CI + ci) * 16 + tap];
}
__device__ inline void dec_tr(const float* __restrict__ src, float* __restrict__ dst,
                              int e, int CI, int CO) {
    int co = e % CO; int r = e / CO; int ci = r % CI; int tap = r / CI;
    dst[e] = src[(co * CI + ci) * 16 + tap];
}

__global__ __launch_bounds__(256) void prep_enc(
    const float* __restrict__ Cs1, const float* __restrict__ Cv1,
    const float* __restrict__ Cs2, const float* __restrict__ Cv2,
    const float* __restrict__ Cs3, const float* __restrict__ Cv3,
    float* __restrict__ ws)
{
    int idx = blockIdx.x * 256 + threadIdx.x;
    if (blockIdx.x == 0) ws[WS_LHOOD + threadIdx.x] = 0.f;   // fold in lhood zeroing
    if (idx < 256)        enc_tr(Cs1, ws + TC_S1, idx,          1, 16);
    else if (idx < 2816)  enc_tr(Cv1, ws + TC_V1, idx - 256,   10, 16);
    else if (idx < 11008) enc_tr(Cs2, ws + TC_S2, idx - 2816,  16, 32);
    else if (idx < 19200) enc_tr(Cv2, ws + TC_V2, idx - 11008, 16, 32);
    else if (idx < 51968) enc_tr(Cs3, ws + TC_S3, idx - 19200, 32, 64);
    else if (idx < 84736) enc_tr(Cv3, ws + TC_V3, idx - 51968, 32, 64);
}

// ---------------- conv1: spatial-split (grid.y = yhalf); zero-padded input tile --------
template<int CIN>
__global__ __launch_bounds__(256) void conv1_lds(
    const float* __restrict__ x, const float* __restrict__ wt,
    const float* __restrict__ bias, float* __restrict__ out)
{
    __shared__ float xin[CIN * 630];   // ci*630 + r*35 + (gx+1), r = local row 0..17
    __shared__ float wl[CIN * 256];
    __shared__ float bl[16];
    int b = blockIdx.x, yh = blockIdx.y, t = threadIdx.x;
    for (int e = t; e < CIN * 576; e += 256) {
        int ci = e / 576;
        int r = (e >> 5) - ci * 18;
        int cx = e & 31;
        int gy = yh * 16 - 1 + r;
        float v = (gy >= 0 && gy < 32) ? x[(size_t)b * 20480 + ci * 1024 + gy * 32 + cx] : 0.f;
        xin[ci * 630 + r * 35 + cx + 1] = v;
    }
    for (int e = t; e < CIN * 18; e += 256) {
        int ci = e / 18, r = e - ci * 18;
        xin[ci * 630 + r * 35 + 0] = 0.f;
        xin[ci * 630 + r * 35 + 33] = 0.f;
    }
    for (int e = t; e < CIN * 256; e += 256) wl[e] = wt[e];
    if (t < 16) bl[t] = bias[t];
    __syncthreads();

    int ocq = t >> 7, p = t & 127;
    int oyl = p >> 4, ox = p & 15;
    float acc[8];
    #pragma unroll
    for (int j = 0; j < 8; j++) acc[j] = bl[ocq * 8 + j];
    for (int ci = 0; ci < CIN; ci++) {
        const float* xc = xin + ci * 630;
        const float* wc = wl + ci * 256 + ocq * 8;
        #pragma unroll
        for (int ky = 0; ky < 4; ky++) {
            const float* xr = xc + (2 * oyl + ky) * 35;
            #pragma unroll
            for (int kx = 0; kx < 4; kx++) {
                float v = xr[2 * ox + kx];     // (ix+1) = 2ox-1+kx+1
                const float4* w4 = (const float4*)(wc + (ky * 4 + kx) * 16);
                float4 wa = w4[0], wb = w4[1];
                acc[0] = fmaf(v, wa.x, acc[0]);
                acc[1] = fmaf(v, wa.y, acc[1]);
                acc[2] = fmaf(v, wa.z, acc[2]);
                acc[3] = fmaf(v, wa.w, acc[3]);
                acc[4] = fmaf(v, wb.x, acc[4]);
                acc[5] = fmaf(v, wb.y, acc[5]);
                acc[6] = fmaf(v, wb.z, acc[6]);
                acc[7] = fmaf(v, wb.w, acc[7]);
            }
        }
    }
    int oy = yh * 8 + oyl;
    size_t ob = (size_t)b * 4096 + (size_t)(ocq * 8) * 256 + oy * 16 + ox;
    #pragma unroll
    for (int j = 0; j < 8; j++) out[ob + (size_t)j * 256] = fmaxf(acc[j], 0.f);
}

// ---------------- conv2: oc-split (grid.y = half) ----------------
__global__ __launch_bounds__(256) void conv2_lds(
    const float* __restrict__ a1, const float* __restrict__ wt,  // wt: [ci][tap][32]
    const float* __restrict__ bias, float* __restrict__ out)
{
    __shared__ float xin[16 * 272];
    __shared__ float wl[4096];    // [ci][tap][16oc slice]
    __shared__ float bl[16];
    int b = blockIdx.x, h = blockIdx.y, t = threadIdx.x;
    for (int e = t; e < 4096; e += 256) {
        int ci = e >> 8, r = e & 255, iy = r >> 4, ix = r & 15;
        xin[ci * 272 + iy * 17 + ix] = a1[(size_t)b * 4096 + e];
    }
    for (int e = t; e < 4096; e += 256) {
        int ci = e >> 8, r = e & 255, tap = r >> 4, oc = r & 15;
        wl[e] = wt[ci * 512 + tap * 32 + h * 16 + oc];
    }
    if (t < 16) bl[t] = bias[h * 16 + t];
    __syncthreads();

    int ocq = t >> 6, p = t & 63;      // 4 groups x 4 oc
    int pa = p >> 3, pb = p & 7;       // oy, ox
    float acc[4];
    #pragma unroll
    for (int j = 0; j < 4; j++) acc[j] = bl[ocq * 4 + j];
    for (int ci = 0; ci < 16; ci++) {
        const float* xc = xin + ci * 272;
        const float* wc = wl + ci * 256 + ocq * 4;
        #pragma unroll
        for (int ky = 0; ky < 4; ky++) {
            int iy = 2 * pa - 1 + ky;
            if ((unsigned)iy >= 16u) continue;
            const float* xr = xc + iy * 17;
            #pragma unroll
            for (int kx = 0; kx < 4; kx++) {
                int ix = 2 * pb - 1 + kx;
                if ((unsigned)ix >= 16u) continue;
                float v = xr[ix];
                float4 wv = *(const float4*)(wc + (ky * 4 + kx) * 16);
                acc[0] = fmaf(v, wv.x, acc[0]);
                acc[1] = fmaf(v, wv.y, acc[1]);
                acc[2] = fmaf(v, wv.z, acc[2]);
                acc[3] = fmaf(v, wv.w, acc[3]);
            }
        }
    }
    size_t ob = (size_t)b * 2048 + (size_t)(h * 16 + ocq * 4) * 64 + pa * 8 + pb;
    #pragma unroll
    for (int j = 0; j < 4; j++) out[ob + (size_t)j * 64] = fmaxf(acc[j], 0.f);
}

// ---------------- conv3 (unchanged) ----------------
__global__ __launch_bounds__(256) void conv3_lds(
    const float* __restrict__ a2, const float* __restrict__ wt,
    const float* __restrict__ bias, float* __restrict__ out)
{
    __shared__ float xin[32 * 72];
    __shared__ float wl[16384];
    __shared__ float bl[32];
    int b = blockIdx.x, h = blockIdx.y, t = threadIdx.x;
    for (int e = t; e < 2048; e += 256) {
        int ci = e >> 6, r = e & 63, iy = r >> 3, ix = r & 7;
        xin[ci * 72 + iy * 9 + ix] = a2[(size_t)b * 2048 + e];
    }
    for (int e4 = t; e4 < 4096; e4 += 256) {
        int grp = e4 >> 3, c4 = e4 & 7;
        ((float4*)wl)[e4] = ((const float4*)(wt + grp * 64 + h * 32))[c4];
    }
    if (t < 32) bl[t] = bias[h * 32 + t];
    __syncthreads();

    int ocq = t >> 4, p = t & 15;
    int pa = p >> 2, pb = p & 3;
    float a0 = bl[ocq * 2], a1 = bl[ocq * 2 + 1];
    for (int ci = 0; ci < 32; ci++) {
        const float* xc = xin + ci * 72;
        const float* wc = wl + ci * 512 + ocq * 2;
        #pragma unroll
        for (int ky = 0; ky < 4; ky++) {
            int iy = 2 * pa - 1 + ky;
            if ((unsigned)iy >= 8u) continue;
            const float* xr = xc + iy * 9;
            #pragma unroll
            for (int kx = 0; kx < 4; kx++) {
                int ix = 2 * pb - 1 + kx;
                if ((unsigned)ix >= 8u) continue;
                float v = xr[ix];
                float2 wv = *(const float2*)(wc + (ky * 4 + kx) * 32);
                a0 = fmaf(v, wv.x, a0);
                a1 = fmaf(v, wv.y, a1);
            }
        }
    }
    size_t ob = (size_t)b * 1024 + (size_t)(h * 32 + ocq * 2) * 16 + pa * 4 + pb;
    out[ob] = fmaxf(a0, 0.f);
    out[ob + 16] = fmaxf(a1, 0.f);
}

// ---------------- encoder fc ----------------
__global__ __launch_bounds__(256) void fc_enc2(
    const float* __restrict__ h,
    const float* __restrict__ Wm, const float* __restrict__ bm,
    const float* __restrict__ Wl, const float* __restrict__ bl,
    float* __restrict__ mu, float* __restrict__ lv)
{
    __shared__ float pm[8][32], pl[8][32];
    int b = blockIdx.x, t = threadIdx.x;
    int q = t & 31, c = t >> 5;
    const float* hb = h + (size_t)b * HDIM_S + c * 128;
    const float* wmp = Wm + (c * 128) * Q_S + q;
    const float* wlp = Wl + (c * 128) * Q_S + q;
    float am = 0.f, al = 0.f;
    #pragma unroll 4
    for (int k = 0; k < 128; k++) {
        float hv = hb[k];
        am = fmaf(hv, wmp[k * Q_S], am);
        al = fmaf(hv, wlp[k * Q_S], al);
    }
    pm[c][q] = am; pl[c][q] = al;
    __syncthreads();
    if (t < 32) {
        float s = bm[t];
        #pragma unroll
        for (int c2 = 0; c2 < 8; c2++) s += pm[c2][t];
        mu[b * Q_S + t] = s;
    } else if (t < 64) {
        int qq = t - 32;
        float s = bl[qq];
        #pragma unroll
        for (int c2 = 0; c2 < 8; c2++) s += pl[c2][qq];
        lv[b * Q_S + qq] = s;
    }
}

// ---------------- reparameterize + decoder weight transpose (fused) ----------------
__global__ __launch_bounds__(256) void reparam_prep(
    const float* __restrict__ s0mu, const float* __restrict__ s0lv,
    const float* __restrict__ v0mu, const float* __restrict__ v0lv,
    const float* __restrict__ eps_s, const float* __restrict__ eps_v,
    const float* __restrict__ D1, const float* __restrict__ D2,
    const float* __restrict__ D3,
    float* __restrict__ ws,
    float* __restrict__ qm, float* __restrict__ qlv,
    float* __restrict__ ztL, float* __restrict__ logp)
{
    int n = blockIdx.x, t = threadIdx.x;
    int idx = n * 256 + t;
    if (idx < 32768)      dec_tr(D1, ws + WS_WT1, idx,         64, 32);
    else if (idx < 40960) dec_tr(D2, ws + WS_WT2, idx - 32768, 32, 16);
    else if (idx < 41216) dec_tr(D3, ws + WS_WT3, idx - 40960, 16, 1);
    if (t < 64) {
        int q = t & 31;
        float mu, lvv, ep;
        if (t < 32) { mu = v0mu[n*32+q]; lvv = v0lv[n*32+q]; ep = eps_v[n*32+q]; }
        else        { mu = s0mu[n*32+q]; lvv = s0lv[n*32+q]; ep = eps_s[n*32+q]; }
        float zv = fmaf(ep, expf(lvv), mu);
        qm[n*64 + t]  = mu;
        qlv[n*64 + t] = lvv;
        ztL[(size_t)n * T_S * 64 + t] = zv;
        float e2 = ep * ep;
        #pragma unroll
        for (int off = 32; off; off >>= 1) e2 += __shfl_down(e2, off, 64);
        if (t == 0) logp[n * T_S] = -0.5f * e2 - Q_S * LOG2PI_F;
    }
}

// ---------------- RK4 ODE (chain-split) ----------------
__global__ __launch_bounds__(256) void ode_kernel(
    const float* __restrict__ W1, const float* __restrict__ b1,
    const float* __restrict__ W2, const float* __restrict__ b2,
    float* __restrict__ ztL, float* __restrict__ logp)
{
    __shared__ float W2s[HDYN_S * Q_S];
    __shared__ float zeval[64];
    __shared__ float hsh[HDYN_S];
    __shared__ float dvred[HDYN_S];
    __shared__ float red4[4];
    int n = blockIdx.x;
    int t = threadIdx.x;

    for (int i = t; i < HDYN_S * Q_S; i += 256) W2s[i] = W2[i];
    float w1r[64];
    #pragma unroll
    for (int j = 0; j < 64; j++) w1r[j] = W1[j * HDYN_S + t];
    float b1r = b1[t];
    __syncthreads();
    float ck = 0.f;
    #pragma unroll
    for (int i = 0; i < Q_S; i++) ck = fmaf(w1r[i], W2s[t * Q_S + i], ck);

    size_t zoff = (size_t)n * T_S * 64;
    float zj = 0.f, ksumj = 0.f, zevalj = 0.f, lp = 0.f, lsum = 0.f;
    if (t < 64) { zj = ztL[zoff + t]; zevalj = zj; zeval[t] = zj; }
    if (t == 0) lp = logp[n * T_S];

    const float wc[4] = {1.f, 2.f, 2.f, 1.f};
    const float ac[3] = {0.5f * DT_S, 0.5f * DT_S, DT_S};

    for (int step = 1; step < T_S; step++) {
        for (int e = 0; e < 4; e++) {
            __syncthreads();
            float p0 = 0.f, p1 = 0.f, p2 = 0.f, p3 = 0.f;
            #pragma unroll
            for (int j = 0; j < 16; j++) {
                p0 = fmaf(zeval[j],      w1r[j],      p0);
                p1 = fmaf(zeval[j + 16], w1r[j + 16], p1);
                p2 = fmaf(zeval[j + 32], w1r[j + 32], p2);
                p3 = fmaf(zeval[j + 48], w1r[j + 48], p3);
            }
            float pre = b1r + ((p0 + p1) + (p2 + p3));
            float hk = tanhf(pre);
            hsh[t] = hk;
            float gk = (1.f - hk * hk) * ck;
            #pragma unroll
            for (int off = 32; off; off >>= 1) gk += __shfl_down(gk, off, 64);
            if ((t & 63) == 0) red4[t >> 6] = gk;
            __syncthreads();
            {
                int i = t & 31, p = t >> 5;
                float a0 = 0.f, a1 = 0.f;
                #pragma unroll
                for (int kk = 0; kk < 16; kk++) {
                    a0 = fmaf(hsh[p * 32 + kk],      W2s[(p * 32 + kk) * Q_S + i],      a0);
                    a1 = fmaf(hsh[p * 32 + 16 + kk], W2s[(p * 32 + 16 + kk) * Q_S + i], a1);
                }
                dvred[t] = a0 + a1;
            }
            __syncthreads();
            if (t < 64) {
                float tr = red4[0] + red4[1] + red4[2] + red4[3];
                float zv_shfl = __shfl(zevalj, (t >= 32) ? (t - 32) : t, 64);
                float kzv;
                if (t < 32) {
                    float dvi = b2[t];
                    #pragma unroll
                    for (int p = 0; p < 8; p++) dvi += dvred[p * 32 + t];
                    kzv = dvi;
                } else kzv = zv_shfl;
                if (e == 0) ksumj = kzv; else ksumj = fmaf(wc[e], kzv, ksumj);
                if (t == 0) { float kl = -tr; lsum = (e == 0) ? kl : fmaf(wc[e], kl, lsum); }
                if (e < 3) {
                    zevalj = fmaf(ac[e], kzv, zj);
                    zeval[t] = zevalj;
                } else {
                    zj = fmaf(DT_S / 6.f, ksumj, zj);
                    zevalj = zj; zeval[t] = zj;
                    ztL[zoff + step * 64 + t] = zj;
                    if (t == 0) { lp = fmaf(DT_S / 6.f, lsum, lp); logp[n * T_S + step] = lp; }
                }
            }
        }
    }
}

// ---------------- fused decoder v5 ----------------
// slp: 2-D padded [iy+1 in 0..5]*412 + [ix+1 in 0..5]*68 + ci  (aliased in u2)
// h1p: 4 planes *1300 + [ly+1]*216 + [lx+1]*36 + oc  (2-D padded)
// h2p: 4 planes *1316 + ly*164 + lx*20 + ci  (odd-16B strides; aliased in u2)
// xst: 32 rows * 36 (aliased onto h1p)
__global__ __launch_bounds__(256) void decoder5(
    const float* __restrict__ ztL, const float* __restrict__ Wf, const float* __restrict__ bf,
    const float* __restrict__ wt1, const float* __restrict__ d1,
    const float* __restrict__ wt2, const float* __restrict__ d2,
    const float* __restrict__ wt3, const float* __restrict__ d3,
    const float* __restrict__ X, float* __restrict__ Xrec, float* __restrict__ lhood)
{
    __shared__ float zs[32];
    __shared__ float h1p[5200];
    __shared__ float u2[5264];
    __shared__ float sh4[4];
    float* slp = u2;
    float* h2p = u2;
    float* xst = h1p;
    const int bidx = blockIdx.x;
    const int t = threadIdx.x;
    const int wu = __builtin_amdgcn_readfirstlane(t >> 6);   // wave id, provably uniform
    const int l = t & 63;
    const int py = wu >> 1, px = wu & 1;

    // ---- P0: zero padded LDS + load z ----
    if (t < 32) zs[t] = ztL[(size_t)bidx * 64 + 32 + t];
    {
        float4 z4 = make_float4(0.f, 0.f, 0.f, 0.f);
        for (int e = t; e < 1316; e += 256) ((float4*)u2)[e] = z4;
        for (int e = t; e < 1300; e += 256) ((float4*)h1p)[e] = z4;
    }
    __syncthreads();

    // ---- fc3: s = z_s @ Wf + bf -> slp ----
    {
        float4 acc = ((const float4*)bf)[t];
        const float4* Wf4 = (const float4*)Wf;
        #pragma unroll 4
        for (int q = 0; q < 32; q++) {
            float zq = zs[q];
            float4 wv = Wf4[q * 256 + t];
            acc.x = fmaf(zq, wv.x, acc.x);
            acc.y = fmaf(zq, wv.y, acc.y);
            acc.z = fmaf(zq, wv.z, acc.z);
            acc.w = fmaf(zq, wv.w, acc.w);
        }
        int k0 = t * 4;
        int ci = k0 >> 4, p0 = k0 & 15;
        int iy = p0 >> 2;             // p0 in {0,4,8,12} -> row; j = ix
        float vv[4] = {acc.x, acc.y, acc.z, acc.w};
        #pragma unroll
        for (int j = 0; j < 4; j++)
            slp[(iy + 1) * 412 + (j + 1) * 68 + ci] = vv[j];
    }
    __syncthreads();

    // ---- deconv1: [4,4,64] -> parity planes of [8,8,32]; thread = 2pos x 4oc ----
    {
        int ocq = l >> 3;
        int pp = l & 7;
        int a_ = pp >> 1, b2 = pp & 1;
        float acc0[4], acc1[4];
        #pragma unroll
        for (int j = 0; j < 4; j++) { acc0[j] = d1[ocq * 4 + j]; acc1[j] = acc0[j]; }
        #pragma unroll
        for (int sy = 0; sy < 2; sy++) {
            int ky = py + 2 * sy;
            int iy = a_ + py + sy - 1;          // -1..4, pad covers
            #pragma unroll
            for (int sx = 0; sx < 2; sx++) {
                int kx = px + 2 * sx;
                int ix0 = 2 * b2 + px + sx - 1; // -1..3
                const float4* ip0 = (const float4*)(slp + (iy + 1) * 412 + (ix0 + 1) * 68);
                const float4* ip1 = (const float4*)((const float*)ip0 + 68);
                const float* wb = wt1 + (ky * 4 + kx) * 2048 + ocq * 4;
                #pragma unroll 4
                for (int cc = 0; cc < 16; cc++) {
                    float4 va = ip0[cc];
                    float4 vb = ip1[cc];
                    float av[4] = {va.x, va.y, va.z, va.w};
                    float bv[4] = {vb.x, vb.y, vb.z, vb.w};
                    #pragma unroll
                    for (int r = 0; r < 4; r++) {
                        float4 wv = *(const float4*)(wb + (cc * 4 + r) * 32);
                        acc0[0] = fmaf(av[r], wv.x, acc0[0]); acc1[0] = fmaf(bv[r], wv.x, acc1[0]);
                        acc0[1] = fmaf(av[r], wv.y, acc0[1]); acc1[1] = fmaf(bv[r], wv.y, acc1[1]);
                        acc0[2] = fmaf(av[r], wv.z, acc0[2]); acc1[2] = fmaf(bv[r], wv.z, acc1[2]);
                        acc0[3] = fmaf(av[r], wv.w, acc0[3]); acc1[3] = fmaf(bv[r], wv.w, acc1[3]);
                    }
                }
            }
        }
        float* hp = h1p + (py * 2 + px) * 1300;
        int ox0 = 2 * b2, ox1 = ox0 + 1;
        float4 r0, r1;
        r0.x = fmaxf(acc0[0],0.f); r0.y = fmaxf(acc0[1],0.f); r0.z = fmaxf(acc0[2],0.f); r0.w = fmaxf(acc0[3],0.f);
        r1.x = fmaxf(acc1[0],0.f); r1.y = fmaxf(acc1[1],0.f); r1.z = fmaxf(acc1[2],0.f); r1.w = fmaxf(acc1[3],0.f);
        *(float4*)(hp + (a_ + 1) * 216 + (ox0 + 1) * 36 + ocq * 4) = r0;
        *(float4*)(hp + (a_ + 1) * 216 + (ox1 + 1) * 36 + ocq * 4) = r1;
    }
    __syncthreads();

    // ---- deconv2: thread = 1 pos x ALL 16 oc; weights fully wave-uniform (s_load) ----
    {
        int a = l >> 3, b = l & 7;     // output pos2 in plane (py,px)
        float acc[16];
        #pragma unroll
        for (int j = 0; j < 16; j++) acc[j] = d2[j];
        #pragma unroll
        for (int sy = 0; sy < 2; sy++) {
            int ky = py + 2 * sy;
            int iyf = a + py + sy - 1;          // -1..8 full h1 coords
            int pyi = iyf & 1, ly = iyf >> 1;   // arithmetic shift: -1 -> -1
            #pragma unroll
            for (int sx = 0; sx < 2; sx++) {
                int kx = px + 2 * sx;
                int ixf = b + px + sx - 1;
                int pxi = ixf & 1, lx = ixf >> 1;
                const float4* ip4 = (const float4*)(h1p + (pyi * 2 + pxi) * 1300
                                                    + (ly + 1) * 216 + (lx + 1) * 36);
                const float* wb = wt2 + (ky * 4 + kx) * 512;   // uniform
                #pragma unroll 2
                for (int cc = 0; cc < 8; cc++) {
                    float4 v = ip4[cc];
                    float vv[4] = {v.x, v.y, v.z, v.w};
                    #pragma unroll
                    for (int r = 0; r < 4; r++) {
                        const float4* wq = (const float4*)(wb + (cc * 4 + r) * 16);
                        float4 w0 = wq[0], w1 = wq[1], w2 = wq[2], w3 = wq[3];
                        float vr = vv[r];
                        acc[0]  = fmaf(vr, w0.x, acc[0]);
                        acc[1]  = fmaf(vr, w0.y, acc[1]);
                        acc[2]  = fmaf(vr, w0.z, acc[2]);
                        acc[3]  = fmaf(vr, w0.w, acc[3]);
                        acc[4]  = fmaf(vr, w1.x, acc[4]);
                        acc[5]  = fmaf(vr, w1.y, acc[5]);
                        acc[6]  = fmaf(vr, w1.z, acc[6]);
                        acc[7]  = fmaf(vr, w1.w, acc[7]);
                        acc[8]  = fmaf(vr, w2.x, acc[8]);
                        acc[9]  = fmaf(vr, w2.y, acc[9]);
                        acc[10] = fmaf(vr, w2.z, acc[10]);
                        acc[11] = fmaf(vr, w2.w, acc[11]);
                        acc[12] = fmaf(vr, w3.x, acc[12]);
                        acc[13] = fmaf(vr, w3.y, acc[13]);
                        acc[14] = fmaf(vr, w3.z, acc[14]);
                        acc[15] = fmaf(vr, w3.w, acc[15]);
                    }
                }
            }
        }
        __syncthreads();   // slp (aliased with h2p) reads fully done block-wide
        float* hq = h2p + (py * 2 + px) * 1316 + a * 164 + b * 20;
        #pragma unroll
        for (int j = 0; j < 4; j++) {
            float4 r;
            r.x = fmaxf(acc[j*4+0], 0.f);
            r.y = fmaxf(acc[j*4+1], 0.f);
            r.z = fmaxf(acc[j*4+2], 0.f);
            r.w = fmaxf(acc[j*4+3], 0.f);
            *(float4*)(hq + j * 4) = r;
        }
    }
    __syncthreads();

    // ---- deconv3: parity [16,16,16] -> [32,32]; weights via uniform s_load ----
    {
        int oy2 = l >> 2, b3 = l & 3;
        float acc[4];
        float d30 = d3[0];
        #pragma unroll
        for (int k = 0; k < 4; k++) acc[k] = d30;
        #pragma unroll
        for (int sy = 0; sy < 2; sy++) {
            int ky = py + 2 * sy;
            int iy = oy2 + py + sy - 1;
            if ((unsigned)iy >= 16u) continue;
            int pyi = iy & 1, ly = iy >> 1;
            #pragma unroll
            for (int sx = 0; sx < 2; sx++) {
                int kx = px + 2 * sx;
                int cx = px + sx - 1;
                const float* wvp = wt3 + (ky * 4 + kx) * 16;   // uniform
                #pragma unroll
                for (int k = 0; k < 4; k++) {
                    int ix = b3 + 4 * k + cx;
                    if ((unsigned)ix >= 16u) continue;
                    int pxi = ix & 1, lx = ix >> 1;
                    const float4* in4 = (const float4*)(h2p + (pyi*2+pxi)*1316 + ly*164 + lx*20);
                    #pragma unroll
                    for (int cc = 0; cc < 4; cc++) {
                        float4 v = in4[cc];
                        float4 wq = ((const float4*)wvp)[cc];
                        acc[k] = fmaf(v.x, wq.x, acc[k]);
                        acc[k] = fmaf(v.y, wq.y, acc[k]);
                        acc[k] = fmaf(v.z, wq.z, acc[k]);
                        acc[k] = fmaf(v.w, wq.w, acc[k]);
                    }
                }
            }
        }
        int oy = 2 * oy2 + py;
        #pragma unroll
        for (int k = 0; k < 4; k++) {
            int ox = 2 * (b3 + 4 * k) + px;
            xst[oy * 36 + ox] = 1.f / (1.f + expf(-acc[k]));
        }
    }
    __syncthreads();

    // ---- coalesced Xrec write + X read + lhood ----
    {
        int row = t >> 3, col = (t & 7) * 4;
        float4 xr4 = *(const float4*)(xst + row * 36 + col);
        *(float4*)(Xrec + (size_t)bidx * 1024 + t * 4) = xr4;
        float4 xi4 = *(const float4*)(X + (size_t)bidx * 1024 + t * 4);
        float ll = 0.f;
        ll += logf(0.001f + xr4.x) * xi4.x + logf(1.001f - xr4.x) * (1.f - xi4.x);
        ll += logf(0.001f + xr4.y) * xi4.y + logf(1.001f - xr4.y) * (1.f - xi4.y);
        ll += logf(0.001f + xr4.z) * xi4.z + logf(1.001f - xr4.z) * (1.f - xi4.z);
        ll += logf(0.001f + xr4.w) * xi4.w + logf(1.001f - xr4.w) * (1.f - xi4.w);
        #pragma unroll
        for (int off = 32; off; off >>= 1) ll += __shfl_down(ll, off, 64);
        if ((t & 63) == 0) sh4[t >> 6] = ll;
    }
    __syncthreads();
    if (t == 0) atomicAdd(&lhood[bidx / T_S], sh4[0] + sh4[1] + sh4[2] + sh4[3]);
}

// ---------------- kl_z ----------------
__global__ __launch_bounds__(64) void klz_kernel(
    const float* __restrict__ ztL, const float* __restrict__ logp, float* __restrict__ klz)
{
    int n = blockIdx.x, t = threadIdx.x;
    float v = 0.f;
    if (t < T_S) {
        const float* z = ztL + ((size_t)n * T_S + t) * 64;
        float s2 = 0.f;
        #pragma unroll
        for (int j = 0; j < 64; j++) s2 = fmaf(z[j], z[j], s2);
        v = logp[n * T_S + t] - (-0.5f * s2 - Q_S * LOG2PI_F);
    }
    #pragma unroll
    for (int off = 32; off; off >>= 1) v += __shfl_down(v, off, 64);
    if (t == 0) klz[n] = v;
}

// ---------------- final scalars (+ kl_w fused) ----------------
__global__ __launch_bounds__(256) void final2(
    const float* __restrict__ lhood, const float* __restrict__ klz,
    const float* __restrict__ W1, const float* __restrict__ W2,
    const int* __restrict__ Ndata, float* __restrict__ outs)
{
    __shared__ float shA[4], shB[4], shC[4];
    int t = threadIdx.x;
    float a = lhood[t];
    float b = klz[t];
    float c = 0.f;
    for (int i = t; i < 64 * HDYN_S; i += 256) c = fmaf(W1[i], W1[i], c);
    for (int i = t; i < HDYN_S * Q_S; i += 256) c = fmaf(W2[i], W2[i], c);
    #pragma unroll
    for (int off = 32; off; off >>= 1) {
        a += __shfl_down(a, off, 64);
        b += __shfl_down(b, off, 64);
        c += __shfl_down(c, off, 64);
    }
    if ((t & 63) == 0) { shA[t >> 6] = a; shB[t >> 6] = b; shC[t >> 6] = c; }
    __syncthreads();
    if (t == 0) {
        float Nd = (float)Ndata[0];
        float lh = Nd * ((shA[0] + shA[1] + shA[2] + shA[3]) / 256.f);
        float kz = Nd * ((shB[0] + shB[1] + shB[2] + shB[3]) / 256.f);
        float bkw = 0.5f * (shC[0] + shC[1] + shC[2] + shC[3]);
        outs[0] = lh - kz - bkw;
        outs[1] = lh;
        outs[2] = kz;
        outs[3] = bkw;
    }
}

extern "C" void kernel_launch(void* const* d_in, const int* in_sizes, int n_in,
                              void* d_out, int out_size, void* d_ws, size_t ws_size,
                              hipStream_t stream) {
    const float* X      = (const float*)d_in[0];
    const float* eps_s0 = (const float*)d_in[1];
    const float* eps_v0 = (const float*)d_in[2];
    const float* Cs1 = (const float*)d_in[3],  *cs1 = (const float*)d_in[4];
    const float* Cs2 = (const float*)d_in[5],  *cs2 = (const float*)d_in[6];
    const float* Cs3 = (const float*)d_in[7],  *cs3 = (const float*)d_in[8];
    const float* Wsm = (const float*)d_in[9],  *bsm = (const float*)d_in[10];
    const float* Wsl = (const float*)d_in[11], *bsl = (const float*)d_in[12];
    const float* Cv1 = (const float*)d_in[13], *cv1 = (const float*)d_in[14];
    const float* Cv2 = (const float*)d_in[15], *cv2 = (const float*)d_in[16];
    const float* Cv3 = (const float*)d_in[17], *cv3 = (const float*)d_in[18];
    const float* Wvm = (const float*)d_in[19], *bvm = (const float*)d_in[20];
    const float* Wvl = (const float*)d_in[21], *bvl = (const float*)d_in[22];
    const float* W1  = (const float*)d_in[23], *b1  = (const float*)d_in[24];
    const float* W2  = (const float*)d_in[25], *b2  = (const float*)d_in[26];
    const float* Wf  = (const float*)d_in[27], *bf  = (const float*)d_in[28];
    const float* D1  = (const float*)d_in[29], *d1  = (const float*)d_in[30];
    const float* D2  = (const float*)d_in[31], *d2  = (const float*)d_in[32];
    const float* D3  = (const float*)d_in[33], *d3  = (const float*)d_in[34];
    const int*   Ndata = (const int*)d_in[35];

    float* out = (float*)d_out;
    float* ws  = (float*)d_ws;

    prep_enc<<<331, 256, 0, stream>>>(Cs1, Cv1, Cs2, Cv2, Cs3, Cv3, ws);

    // ---- encoder s (frame 0) ----
    conv1_lds<1><<<dim3(256, 2), 256, 0, stream>>>(X, ws + TC_S1, cs1, ws + WS_A1);
    conv2_lds<<<dim3(256, 2), 256, 0, stream>>>(ws + WS_A1, ws + TC_S2, cs2, ws + WS_A2);
    conv3_lds<<<dim3(256, 2), 256, 0, stream>>>(ws + WS_A2, ws + TC_S3, cs3, ws + WS_A3);
    fc_enc2<<<256, 256, 0, stream>>>(ws + WS_A3, Wsm, bsm, Wsl, bsl, ws + WS_S0MU, ws + WS_S0LV);

    // ---- encoder v (10 frames as channels) ----
    conv1_lds<10><<<dim3(256, 2), 256, 0, stream>>>(X, ws + TC_V1, cv1, ws + WS_A1);
    conv2_lds<<<dim3(256, 2), 256, 0, stream>>>(ws + WS_A1, ws + TC_V2, cv2, ws + WS_A2);
    conv3_lds<<<dim3(256, 2), 256, 0, stream>>>(ws + WS_A2, ws + TC_V3, cv3, ws + WS_A3);
    fc_enc2<<<256, 256, 0, stream>>>(ws + WS_A3, Wvm, bvm, Wvl, bvl, ws + WS_V0MU, ws + WS_V0LV);

    // ---- reparameterize + decoder weight transpose (A-regions now dead) ----
    reparam_prep<<<256, 256, 0, stream>>>(ws + WS_S0MU, ws + WS_S0LV, ws + WS_V0MU, ws + WS_V0LV,
                                          eps_s0, eps_v0, D1, D2, D3, ws,
                                          out + OUT_QM, out + OUT_QLV,
                                          out + OUT_ZT, ws + WS_LOGP);

    // ---- RK4 ODE ----
    ode_kernel<<<256, 256, 0, stream>>>(W1, b1, W2, b2, out + OUT_ZT, ws + WS_LOGP);

    // ---- fused decoder ----
    decoder5<<<5120, 256, 0, stream>>>(out + OUT_ZT, Wf, bf,
                                       ws + WS_WT1, d1, ws + WS_WT2, d2, ws + WS_WT3, d3,
                                       X, out + OUT_XREC, ws + WS_LHOOD);

    // ---- ELBO pieces ----
    klz_kernel<<<256, 64, 0, stream>>>(out + OUT_ZT, ws + WS_LOGP, ws + WS_KLZ);
    final2<<<1, 256, 0, stream>>>(ws + WS_LHOOD, ws + WS_KLZ, W1, W2, Ndata,
                                  out + OUT_SCAL);
}